// Round 9
// baseline (543.404 us; speedup 1.0000x reference)
//
#include <hip/hip_runtime.h>
#include <stdint.h>
#include <stddef.h>

typedef __bf16 bf16;
typedef bf16 bf16x8 __attribute__((ext_vector_type(8)));
typedef bf16 bf16x4 __attribute__((ext_vector_type(4)));
typedef float f32x4 __attribute__((ext_vector_type(4)));

#define B_   16
#define CI   192
#define CO   192
#define H_   128
#define W_   128
#define KE   8
#define LD   64
#define KTOT 1728   // 9*192
#define HP   130    // padded H/W
#define HPHP (HP*HP)
#define NPX  (H_*W_)
#define NT   54     // K micro-steps of 32 (order: r-major, ib, s-minor)

__device__ __forceinline__ void gll16(const void* g, void* l) {
  __builtin_amdgcn_global_load_lds(
      (const __attribute__((address_space(1))) unsigned int*)g,
      (__attribute__((address_space(3))) unsigned int*)l, 16, 0, 0);
}

__device__ __forceinline__ float silu_f(float x) {
  return x / (1.f + __expf(-x));
}

// ---------------- attention softmax: latent[16,64] -> attn[16,8] ----------------
__global__ void k_attn(const float* __restrict__ latent, const float* __restrict__ attn_w,
                       const float* __restrict__ attn_b, float* __restrict__ attn) {
  int t = threadIdx.x;           // 128 threads: b = t>>3, k = t&7
  int b = t >> 3, k = t & 7;
  float s = attn_b[k];
  for (int d = 0; d < LD; ++d) s += latent[b*LD + d] * attn_w[k*LD + d];
  float m = s;
  for (int off = 4; off; off >>= 1) m = fmaxf(m, __shfl_xor(m, off, 8));
  float e = __expf(s - m);
  float sum = e;
  for (int off = 4; off; off >>= 1) sum += __shfl_xor(sum, off, 8);
  attn[t] = e / sum;
}

// ---------------- dynamic bias ----------------
__global__ void k_bdyn(const float* __restrict__ attn, const float* __restrict__ expert_b,
                       float* __restrict__ bdyn) {
  int j = blockIdx.x * 256 + threadIdx.x;
  if (j >= B_ * CO) return;
  int b = j / CO, o = j - b * CO;
  float s = 0.f;
  #pragma unroll
  for (int e = 0; e < KE; ++e) s += attn[b*KE + e] * expert_b[e*CO + o];
  bdyn[j] = s;
}

// ---------------- dynamic weights -> staged layout [b][kt=54][chunk=12][slot=64][8] bf16
// K order: kt = r*18 + ib*3 + s  (s innermost). slot L holds (row=L>>2, ks=(L&3)^((row>>1)&3)).
// element: o = chunk*16+row, i = ib*32 + ks*8 + j, weight (o, i, r, s).
__global__ void k_wdyn(const float* __restrict__ expert_w, const float* __restrict__ attn,
                       bf16* __restrict__ w_re) {
  int o = blockIdx.x;            // 192
  int chunk = o >> 4, row = o & 15, c = (row >> 1) & 3;
  __shared__ float ew[KE][KTOT];
  __shared__ float al[B_][KE];
  for (int e = 0; e < KE; ++e)
    for (int j = threadIdx.x; j < KTOT; j += 256)
      ew[e][j] = expert_w[((size_t)e*CO + o)*KTOT + j];   // [i*9+rs]
  if (threadIdx.x < B_*KE) al[threadIdx.x >> 3][threadIdx.x & 7] = attn[threadIdx.x];
  __syncthreads();
  for (int idx = threadIdx.x; idx < B_*KTOT; idx += 256) {
    int b = idx / KTOT, k = idx - b*KTOT;
    int kt = k >> 5, ks = (k >> 3) & 3, j = k & 7;
    int r = kt / 18, t2 = kt - r*18;
    int ibb = t2 / 3, s = t2 - ibb*3;
    int i = ibb*32 + ks*8 + j;
    float acc = 0.f;
    #pragma unroll
    for (int e = 0; e < KE; ++e) acc += al[b][e] * ew[e][i*9 + r*3 + s];
    int slot = row*4 + (ks ^ c);
    w_re[((((size_t)b*NT + kt)*12 + chunk)*64 + slot)*8 + j] = (bf16)acc;
  }
}

// ---------------- static conv2 weights -> same staged layout (no b) ----------------
__global__ void k_w2re(const float* __restrict__ conv2_w, bf16* __restrict__ w2_re) {
  int o = blockIdx.x;
  int chunk = o >> 4, row = o & 15, c = (row >> 1) & 3;
  __shared__ float cw[KTOT];
  for (int j = threadIdx.x; j < KTOT; j += 256) cw[j] = conv2_w[(size_t)o*KTOT + j];
  __syncthreads();
  for (int k = threadIdx.x; k < KTOT; k += 256) {
    int kt = k >> 5, ks = (k >> 3) & 3, j = k & 7;
    int r = kt / 18, t2 = kt - r*18;
    int ibb = t2 / 3, s = t2 - ibb*3;
    int i = ibb*32 + ks*8 + j;
    int slot = row*4 + (ks ^ c);
    w2_re[(((size_t)kt*12 + chunk)*64 + slot)*8 + j] = (bf16)cw[i*9 + r*3 + s];
  }
}

// ---------------- pack+pad x: f32 NCHW -> bf16 [b][i/8][130][130][8], zero borders ----------------
__global__ void k_xpack(const float* __restrict__ x, bf16* __restrict__ xpack) {
  int h2 = blockIdx.x, ib = blockIdx.y, b = blockIdx.z;
  size_t rowbase = (((size_t)b*24 + ib)*HP + h2)*HP;
  int t = threadIdx.x;  // 128
  if (h2 == 0 || h2 == HP-1) {
    uint4 z = make_uint4(0,0,0,0);
    for (int w = t; w < HP; w += 128) *(uint4*)(xpack + (rowbase + w)*8) = z;
    return;
  }
  __shared__ float tt[8][128];
  int h = h2 - 1;
  #pragma unroll
  for (int ii = 0; ii < 8; ++ii)
    tt[ii][t] = x[(((size_t)b*CI + ib*8 + ii)*H_ + h)*W_ + t];
  __syncthreads();
  bf16x8 v;
  #pragma unroll
  for (int ii = 0; ii < 8; ++ii) v[ii] = (bf16)tt[ii][t];
  *(bf16x8*)(xpack + (rowbase + t + 1)*8) = v;
  if (t == 0) {
    uint4 z = make_uint4(0,0,0,0);
    *(uint4*)(xpack + rowbase*8) = z;
    *(uint4*)(xpack + (rowbase + HP-1)*8) = z;
  }
}

// ---------------- zero borders of midpack ----------------
__global__ void k_midborder(bf16* __restrict__ midpack) {
  int bi = blockIdx.x;  // b*24+ib
  size_t base = (size_t)bi * HPHP;
  uint4 z = make_uint4(0,0,0,0);
  for (int j = threadIdx.x; j < 516; j += 256) {
    int h2, w2;
    if (j < 130)      { h2 = 0;       w2 = j; }
    else if (j < 260) { h2 = 129;     w2 = j - 130; }
    else if (j < 388) { h2 = j - 259; w2 = 0; }
    else              { h2 = j - 387; w2 = 129; }
    *(uint4*)(midpack + (base + (size_t)h2*HP + w2)*8) = z;
  }
}

// ---------------- implicit-GEMM 3x3 conv, BM=192 x BN=256(2 rows), K order (r,ib,s) ----------------
// 4 waves (2m x 2n), per-wave 96x128. 18 macros (r,ib) x 3 micros (s).
// A: loaded per-micro straight from L2 into transient register fragments (no A-LDS,
//    no ping-pong -> no spill). B: row-pair staged per macro into LDS (2 buffers,
//    kg-stride 2080 el); s served by +16B shift on the ds_read.
// ONE __syncthreads per macro; no intra-macro barriers (B read-only within macro,
// af private) -> waves desync across micros and interleave pipes.
// VMEM FIFO per wave per macro: [af(s0)6][af(s1)6][af(s2)6, B(m+1)5] -- af is always
// newest when waited, so compiler's counted vmcnt drains af exactly; B(m+1) stays
// in flight through s2's MFMA burst and is drained by next macro's __syncthreads.
template<int MODE>
__global__ __launch_bounds__(256, 2)
void k_conv(const bf16* __restrict__ wre, const bf16* __restrict__ inpack,
            const float* __restrict__ bias_g, const bf16* __restrict__ respack,
            bf16* __restrict__ outpack, float* __restrict__ outp) {
  const int tid  = threadIdx.x;
  const int lane = tid & 63;
  const int wv   = tid >> 6;          // 0..3
  const int wm   = wv >> 1;           // 0..1 (o half)
  const int wn   = wv & 1;            // 0..1 (p half = image row)
  const int l15  = lane & 15, l4 = lane >> 4;

  // XCD-aware chunked remap: 1024 blocks, 128/XCD => each XCD owns 2 batches
  const int bid  = blockIdx.x;
  const int n    = (bid & 7) * 128 + (bid >> 3);
  const int b    = n >> 6;
  const int tile = n & 63;
  const int p0   = tile * 256;
  const int h0   = tile * 2;

  __shared__ __align__(16) bf16 Blds[2][4*2080];    // 33280 B
  __shared__ float bias_lds[CO];

  const size_t wbase = (MODE == 0) ? ((size_t)b*CO*KTOT) : 0;

  // B staging: wave wv stages kg=wv; 5 overlapped 1KB chunks over contiguous row-pair (4160B)
  const bf16* bbase = inpack + (((size_t)b*24 + wv)*HPHP + (size_t)h0*HP)*8 + lane*8;
  int ibm = 0; ptrdiff_t boffEl = 0;   // macro (r,ib) element offset

  auto stageB = [&](bf16* dbuf) {
    const bf16* src = bbase + boffEl;
    bf16* d = dbuf + wv*2080;
    gll16(src,        d);
    gll16(src +  512, d +  512);
    gll16(src + 1024, d + 1024);
    gll16(src + 1536, d + 1536);
    gll16(src + 1568, d + 1568);   // tail chunk (el 1568..2079); overlap re-writes same data
    if (++ibm == 6) { ibm = 0; boffEl += (ptrdiff_t)(HP - 20*HPHP)*8; }
    else boffEl += (ptrdiff_t)4*HPHP*8;
  };

  // stage B(0) as early as possible
  stageB((bf16*)Blds[0]);

  if (tid < CO) bias_lds[tid] = (MODE == 0) ? bias_g[b*CO + tid] : bias_g[tid];

  // A: per-lane global pointer; sw un-permutes the baked slot swizzle (coalesced 1KB/chunk)
  const int sw = l15*4 + (l4 ^ ((l15 >> 1) & 3));
  const bf16* aptr = wre + wbase + (size_t)(wm*6)*512 + (size_t)sw*8;

  f32x4 acc[6][8];
  #pragma unroll
  for (int mf = 0; mf < 6; ++mf)
    #pragma unroll
    for (int nf = 0; nf < 8; ++nf)
      #pragma unroll
      for (int jj = 0; jj < 4; ++jj) acc[mf][nf][jj] = 0.f;

  const int bvb = l4*2080 + (wn*130 + l15)*8;           // B read base (elements)

  bf16* Bcur = (bf16*)Blds[0];
  bf16* Bnxt = (bf16*)Blds[1];

  // one micro: af (global->reg, transient) + bv (LDS) + 48 MFMA
  auto micro = [&](const bf16* Bc, int s, bool dostage, bf16* stagebuf) {
    bf16x8 af0 = *(const bf16x8*)(aptr);
    bf16x8 af1 = *(const bf16x8*)(aptr +  512);
    bf16x8 af2 = *(const bf16x8*)(aptr + 1024);
    bf16x8 af3 = *(const bf16x8*)(aptr + 1536);
    bf16x8 af4 = *(const bf16x8*)(aptr + 2048);
    bf16x8 af5 = *(const bf16x8*)(aptr + 2560);
    aptr += 6144;
    if (dostage) stageB(stagebuf);        // issued AFTER af: af drains without draining B
    const bf16* bp = Bc + bvb + s*8;
    bf16x8 bv0 = *(const bf16x8*)(bp);
    bf16x8 bv1 = *(const bf16x8*)(bp + 128);
    bf16x8 bv2 = *(const bf16x8*)(bp + 256);
    bf16x8 bv3 = *(const bf16x8*)(bp + 384);
    bf16x8 bv4 = *(const bf16x8*)(bp + 512);
    bf16x8 bv5 = *(const bf16x8*)(bp + 640);
    bf16x8 bv6 = *(const bf16x8*)(bp + 768);
    bf16x8 bv7 = *(const bf16x8*)(bp + 896);
    __builtin_amdgcn_s_setprio(1);
    acc[0][0] = __builtin_amdgcn_mfma_f32_16x16x32_bf16(af0, bv0, acc[0][0], 0, 0, 0);
    acc[1][0] = __builtin_amdgcn_mfma_f32_16x16x32_bf16(af1, bv0, acc[1][0], 0, 0, 0);
    acc[2][0] = __builtin_amdgcn_mfma_f32_16x16x32_bf16(af2, bv0, acc[2][0], 0, 0, 0);
    acc[3][0] = __builtin_amdgcn_mfma_f32_16x16x32_bf16(af3, bv0, acc[3][0], 0, 0, 0);
    acc[4][0] = __builtin_amdgcn_mfma_f32_16x16x32_bf16(af4, bv0, acc[4][0], 0, 0, 0);
    acc[5][0] = __builtin_amdgcn_mfma_f32_16x16x32_bf16(af5, bv0, acc[5][0], 0, 0, 0);
    acc[0][1] = __builtin_amdgcn_mfma_f32_16x16x32_bf16(af0, bv1, acc[0][1], 0, 0, 0);
    acc[1][1] = __builtin_amdgcn_mfma_f32_16x16x32_bf16(af1, bv1, acc[1][1], 0, 0, 0);
    acc[2][1] = __builtin_amdgcn_mfma_f32_16x16x32_bf16(af2, bv1, acc[2][1], 0, 0, 0);
    acc[3][1] = __builtin_amdgcn_mfma_f32_16x16x32_bf16(af3, bv1, acc[3][1], 0, 0, 0);
    acc[4][1] = __builtin_amdgcn_mfma_f32_16x16x32_bf16(af4, bv1, acc[4][1], 0, 0, 0);
    acc[5][1] = __builtin_amdgcn_mfma_f32_16x16x32_bf16(af5, bv1, acc[5][1], 0, 0, 0);
    acc[0][2] = __builtin_amdgcn_mfma_f32_16x16x32_bf16(af0, bv2, acc[0][2], 0, 0, 0);
    acc[1][2] = __builtin_amdgcn_mfma_f32_16x16x32_bf16(af1, bv2, acc[1][2], 0, 0, 0);
    acc[2][2] = __builtin_amdgcn_mfma_f32_16x16x32_bf16(af2, bv2, acc[2][2], 0, 0, 0);
    acc[3][2] = __builtin_amdgcn_mfma_f32_16x16x32_bf16(af3, bv2, acc[3][2], 0, 0, 0);
    acc[4][2] = __builtin_amdgcn_mfma_f32_16x16x32_bf16(af4, bv2, acc[4][2], 0, 0, 0);
    acc[5][2] = __builtin_amdgcn_mfma_f32_16x16x32_bf16(af5, bv2, acc[5][2], 0, 0, 0);
    acc[0][3] = __builtin_amdgcn_mfma_f32_16x16x32_bf16(af0, bv3, acc[0][3], 0, 0, 0);
    acc[1][3] = __builtin_amdgcn_mfma_f32_16x16x32_bf16(af1, bv3, acc[1][3], 0, 0, 0);
    acc[2][3] = __builtin_amdgcn_mfma_f32_16x16x32_bf16(af2, bv3, acc[2][3], 0, 0, 0);
    acc[3][3] = __builtin_amdgcn_mfma_f32_16x16x32_bf16(af3, bv3, acc[3][3], 0, 0, 0);
    acc[4][3] = __builtin_amdgcn_mfma_f32_16x16x32_bf16(af4, bv3, acc[4][3], 0, 0, 0);
    acc[5][3] = __builtin_amdgcn_mfma_f32_16x16x32_bf16(af5, bv3, acc[5][3], 0, 0, 0);
    acc[0][4] = __builtin_amdgcn_mfma_f32_16x16x32_bf16(af0, bv4, acc[0][4], 0, 0, 0);
    acc[1][4] = __builtin_amdgcn_mfma_f32_16x16x32_bf16(af1, bv4, acc[1][4], 0, 0, 0);
    acc[2][4] = __builtin_amdgcn_mfma_f32_16x16x32_bf16(af2, bv4, acc[2][4], 0, 0, 0);
    acc[3][4] = __builtin_amdgcn_mfma_f32_16x16x32_bf16(af3, bv4, acc[3][4], 0, 0, 0);
    acc[4][4] = __builtin_amdgcn_mfma_f32_16x16x32_bf16(af4, bv4, acc[4][4], 0, 0, 0);
    acc[5][4] = __builtin_amdgcn_mfma_f32_16x16x32_bf16(af5, bv4, acc[5][4], 0, 0, 0);
    acc[0][5] = __builtin_amdgcn_mfma_f32_16x16x32_bf16(af0, bv5, acc[0][5], 0, 0, 0);
    acc[1][5] = __builtin_amdgcn_mfma_f32_16x16x32_bf16(af1, bv5, acc[1][5], 0, 0, 0);
    acc[2][5] = __builtin_amdgcn_mfma_f32_16x16x32_bf16(af2, bv5, acc[2][5], 0, 0, 0);
    acc[3][5] = __builtin_amdgcn_mfma_f32_16x16x32_bf16(af3, bv5, acc[3][5], 0, 0, 0);
    acc[4][5] = __builtin_amdgcn_mfma_f32_16x16x32_bf16(af4, bv5, acc[4][5], 0, 0, 0);
    acc[5][5] = __builtin_amdgcn_mfma_f32_16x16x32_bf16(af5, bv5, acc[5][5], 0, 0, 0);
    acc[0][6] = __builtin_amdgcn_mfma_f32_16x16x32_bf16(af0, bv6, acc[0][6], 0, 0, 0);
    acc[1][6] = __builtin_amdgcn_mfma_f32_16x16x32_bf16(af1, bv6, acc[1][6], 0, 0, 0);
    acc[2][6] = __builtin_amdgcn_mfma_f32_16x16x32_bf16(af2, bv6, acc[2][6], 0, 0, 0);
    acc[3][6] = __builtin_amdgcn_mfma_f32_16x16x32_bf16(af3, bv6, acc[3][6], 0, 0, 0);
    acc[4][6] = __builtin_amdgcn_mfma_f32_16x16x32_bf16(af4, bv6, acc[4][6], 0, 0, 0);
    acc[5][6] = __builtin_amdgcn_mfma_f32_16x16x32_bf16(af5, bv6, acc[5][6], 0, 0, 0);
    acc[0][7] = __builtin_amdgcn_mfma_f32_16x16x32_bf16(af0, bv7, acc[0][7], 0, 0, 0);
    acc[1][7] = __builtin_amdgcn_mfma_f32_16x16x32_bf16(af1, bv7, acc[1][7], 0, 0, 0);
    acc[2][7] = __builtin_amdgcn_mfma_f32_16x16x32_bf16(af2, bv7, acc[2][7], 0, 0, 0);
    acc[3][7] = __builtin_amdgcn_mfma_f32_16x16x32_bf16(af3, bv7, acc[3][7], 0, 0, 0);
    acc[4][7] = __builtin_amdgcn_mfma_f32_16x16x32_bf16(af4, bv7, acc[4][7], 0, 0, 0);
    acc[5][7] = __builtin_amdgcn_mfma_f32_16x16x32_bf16(af5, bv7, acc[5][7], 0, 0, 0);
    __builtin_amdgcn_s_setprio(0);
    __builtin_amdgcn_sched_barrier(0);   // pin micro boundary (reg-pressure guard)
  };

  for (int m = 0; m < 18; ++m) {
    __syncthreads();                      // B(m) landed (all waves), prev reads done
    micro(Bcur, 0, false, nullptr);
    micro(Bcur, 1, false, nullptr);
    micro(Bcur, 2, m < 17, Bnxt);         // stage B(m+1) inside s2, after af issue
    { bf16* t = Bcur; Bcur = Bnxt; Bnxt = t; }
  }

  // epilogue
  #pragma unroll
  for (int mf = 0; mf < 6; ++mf) {
    int ob = wm*96 + mf*16 + l4*4;     // output channel base (4 consecutive)
    #pragma unroll
    for (int nf = 0; nf < 8; ++nf) {
      int pl = wn*128 + nf*16 + l15;
      int p  = p0 + pl;
      f32x4 v = acc[mf][nf];
      int h = p >> 7, w = p & 127;
      size_t basep = (((size_t)b*24 + (ob >> 3))*HP + (h + 1))*HP + (w + 1);
      if (MODE == 0) {
        bf16x4 pk;
        #pragma unroll
        for (int jj = 0; jj < 4; ++jj) {
          float xv = v[jj] + bias_lds[ob + jj];
          pk[jj] = (bf16)silu_f(xv);
        }
        *(bf16x4*)(outpack + basep*8 + (ob & 7)) = pk;
      } else {
        bf16x4 rr = *(const bf16x4*)(respack + basep*8 + (ob & 7));
        #pragma unroll
        for (int jj = 0; jj < 4; ++jj) {
          float xv = silu_f(v[jj] + bias_lds[ob + jj]);
          size_t idx = ((size_t)b*CO + ob + jj)*NPX + p;
          outp[idx] = xv + (float)rr[jj];
        }
      }
    }
  }
}

extern "C" void kernel_launch(void* const* d_in, const int* in_sizes, int n_in,
                              void* d_out, int out_size, void* d_ws, size_t ws_size,
                              hipStream_t stream) {
  const float* x        = (const float*)d_in[0];
  const float* latent   = (const float*)d_in[1];
  const float* expert_w = (const float*)d_in[2];
  const float* expert_b = (const float*)d_in[3];
  const float* attn_w   = (const float*)d_in[4];
  const float* attn_b   = (const float*)d_in[5];
  const float* conv2_w  = (const float*)d_in[6];
  const float* conv2_b  = (const float*)d_in[7];
  float* outp = (float*)d_out;

  char* base = (char*)d_ws;
  size_t off = 0;
  float* attn = (float*)(base + off); off += 4096;
  float* bdyn = (float*)(base + off); off += 16384;
  bf16* w_re  = (bf16*)(base + off);  off += (size_t)B_*CO*KTOT*2;      // 10.6 MB
  bf16* w2_re = (bf16*)(base + off);  off += (size_t)CO*KTOT*2;         // 0.66 MB
  bf16* xpack = (bf16*)(base + off);  off += (size_t)B_*24*HPHP*8*2;    // 103.8 MB
  bf16* midpack = (bf16*)(base + off); off += (size_t)B_*24*HPHP*8*2;   // 103.8 MB
  (void)ws_size; (void)in_sizes; (void)n_in; (void)out_size;

  k_attn<<<dim3(1), dim3(128), 0, stream>>>(latent, attn_w, attn_b, attn);
  k_bdyn<<<dim3(12), dim3(256), 0, stream>>>(attn, expert_b, bdyn);
  k_wdyn<<<dim3(CO), dim3(256), 0, stream>>>(expert_w, attn, w_re);
  k_w2re<<<dim3(CO), dim3(256), 0, stream>>>(conv2_w, w2_re);
  k_xpack<<<dim3(130, 24, 16), dim3(128), 0, stream>>>(x, xpack);
  k_midborder<<<dim3(B_*24), dim3(256), 0, stream>>>(midpack);
  k_conv<0><<<dim3(1024), dim3(256), 0, stream>>>(w_re, xpack, bdyn, xpack, midpack, outp);
  k_conv<1><<<dim3(1024), dim3(256), 0, stream>>>(w2_re, midpack, conv2_b, xpack, midpack, outp);
}

// Round 10
// 500.734 us; speedup vs baseline: 1.0852x; 1.0852x over previous
//
#include <hip/hip_runtime.h>
#include <stdint.h>
#include <stddef.h>

typedef __bf16 bf16;
typedef bf16 bf16x8 __attribute__((ext_vector_type(8)));
typedef bf16 bf16x4 __attribute__((ext_vector_type(4)));
typedef float f32x4 __attribute__((ext_vector_type(4)));

#define B_   16
#define CI   192
#define CO   192
#define H_   128
#define W_   128
#define KE   8
#define LD   64
#define KTOT 1728   // 9*192
#define HP   130    // padded H/W
#define HPHP (HP*HP)
#define NPX  (H_*W_)
#define NT   54     // K micro-steps of 32 (order: r-major, ib, s-minor)

__device__ __forceinline__ void gll16(const void* g, void* l) {
  __builtin_amdgcn_global_load_lds(
      (const __attribute__((address_space(1))) unsigned int*)g,
      (__attribute__((address_space(3))) unsigned int*)l, 16, 0, 0);
}

__device__ __forceinline__ float silu_f(float x) {
  return x / (1.f + __expf(-x));
}

// ---------------- attention softmax: latent[16,64] -> attn[16,8] ----------------
__global__ void k_attn(const float* __restrict__ latent, const float* __restrict__ attn_w,
                       const float* __restrict__ attn_b, float* __restrict__ attn) {
  int t = threadIdx.x;           // 128 threads: b = t>>3, k = t&7
  int b = t >> 3, k = t & 7;
  float s = attn_b[k];
  for (int d = 0; d < LD; ++d) s += latent[b*LD + d] * attn_w[k*LD + d];
  float m = s;
  for (int off = 4; off; off >>= 1) m = fmaxf(m, __shfl_xor(m, off, 8));
  float e = __expf(s - m);
  float sum = e;
  for (int off = 4; off; off >>= 1) sum += __shfl_xor(sum, off, 8);
  attn[t] = e / sum;
}

// ---------------- dynamic bias ----------------
__global__ void k_bdyn(const float* __restrict__ attn, const float* __restrict__ expert_b,
                       float* __restrict__ bdyn) {
  int j = blockIdx.x * 256 + threadIdx.x;
  if (j >= B_ * CO) return;
  int b = j / CO, o = j - b * CO;
  float s = 0.f;
  #pragma unroll
  for (int e = 0; e < KE; ++e) s += attn[b*KE + e] * expert_b[e*CO + o];
  bdyn[j] = s;
}

// ---------------- dynamic weights -> staged layout [b][kt=54][chunk=12][slot=64][8] bf16
// K order: kt = r*18 + ib*3 + s  (s innermost). slot L holds (row=L>>2, ks=(L&3)^((row>>1)&3)).
// element: o = chunk*16+row, i = ib*32 + ks*8 + j, weight (o, i, r, s).
__global__ void k_wdyn(const float* __restrict__ expert_w, const float* __restrict__ attn,
                       bf16* __restrict__ w_re) {
  int o = blockIdx.x;            // 192
  int chunk = o >> 4, row = o & 15, c = (row >> 1) & 3;
  __shared__ float ew[KE][KTOT];
  __shared__ float al[B_][KE];
  for (int e = 0; e < KE; ++e)
    for (int j = threadIdx.x; j < KTOT; j += 256)
      ew[e][j] = expert_w[((size_t)e*CO + o)*KTOT + j];   // [i*9+rs]
  if (threadIdx.x < B_*KE) al[threadIdx.x >> 3][threadIdx.x & 7] = attn[threadIdx.x];
  __syncthreads();
  for (int idx = threadIdx.x; idx < B_*KTOT; idx += 256) {
    int b = idx / KTOT, k = idx - b*KTOT;
    int kt = k >> 5, ks = (k >> 3) & 3, j = k & 7;
    int r = kt / 18, t2 = kt - r*18;
    int ibb = t2 / 3, s = t2 - ibb*3;
    int i = ibb*32 + ks*8 + j;
    float acc = 0.f;
    #pragma unroll
    for (int e = 0; e < KE; ++e) acc += al[b][e] * ew[e][i*9 + r*3 + s];
    int slot = row*4 + (ks ^ c);
    w_re[((((size_t)b*NT + kt)*12 + chunk)*64 + slot)*8 + j] = (bf16)acc;
  }
}

// ---------------- static conv2 weights -> same staged layout (no b) ----------------
__global__ void k_w2re(const float* __restrict__ conv2_w, bf16* __restrict__ w2_re) {
  int o = blockIdx.x;
  int chunk = o >> 4, row = o & 15, c = (row >> 1) & 3;
  __shared__ float cw[KTOT];
  for (int j = threadIdx.x; j < KTOT; j += 256) cw[j] = conv2_w[(size_t)o*KTOT + j];
  __syncthreads();
  for (int k = threadIdx.x; k < KTOT; k += 256) {
    int kt = k >> 5, ks = (k >> 3) & 3, j = k & 7;
    int r = kt / 18, t2 = kt - r*18;
    int ibb = t2 / 3, s = t2 - ibb*3;
    int i = ibb*32 + ks*8 + j;
    int slot = row*4 + (ks ^ c);
    w2_re[(((size_t)kt*12 + chunk)*64 + slot)*8 + j] = (bf16)cw[i*9 + r*3 + s];
  }
}

// ---------------- pack+pad x: f32 NCHW -> bf16 [b][i/8][130][130][8], zero borders ----------------
__global__ void k_xpack(const float* __restrict__ x, bf16* __restrict__ xpack) {
  int h2 = blockIdx.x, ib = blockIdx.y, b = blockIdx.z;
  size_t rowbase = (((size_t)b*24 + ib)*HP + h2)*HP;
  int t = threadIdx.x;  // 128
  if (h2 == 0 || h2 == HP-1) {
    uint4 z = make_uint4(0,0,0,0);
    for (int w = t; w < HP; w += 128) *(uint4*)(xpack + (rowbase + w)*8) = z;
    return;
  }
  __shared__ float tt[8][128];
  int h = h2 - 1;
  #pragma unroll
  for (int ii = 0; ii < 8; ++ii)
    tt[ii][t] = x[(((size_t)b*CI + ib*8 + ii)*H_ + h)*W_ + t];
  __syncthreads();
  bf16x8 v;
  #pragma unroll
  for (int ii = 0; ii < 8; ++ii) v[ii] = (bf16)tt[ii][t];
  *(bf16x8*)(xpack + (rowbase + t + 1)*8) = v;
  if (t == 0) {
    uint4 z = make_uint4(0,0,0,0);
    *(uint4*)(xpack + rowbase*8) = z;
    *(uint4*)(xpack + (rowbase + HP-1)*8) = z;
  }
}

// ---------------- zero borders of midpack ----------------
__global__ void k_midborder(bf16* __restrict__ midpack) {
  int bi = blockIdx.x;  // b*24+ib
  size_t base = (size_t)bi * HPHP;
  uint4 z = make_uint4(0,0,0,0);
  for (int j = threadIdx.x; j < 516; j += 256) {
    int h2, w2;
    if (j < 130)      { h2 = 0;       w2 = j; }
    else if (j < 260) { h2 = 129;     w2 = j - 130; }
    else if (j < 388) { h2 = j - 259; w2 = 0; }
    else              { h2 = j - 387; w2 = 129; }
    *(uint4*)(midpack + (base + (size_t)h2*HP + w2)*8) = z;
  }
}

// ---------------- implicit-GEMM 3x3 conv, BM=192 x BN=256(2 rows), K order (r,ib,s) ----------------
// R8 structure + 4-phase micro (T3 finer split) + stageB moved to s0 (longer B lead).
// 4 waves (2m x 2n), per-wave 96x128. 18 macros (r,ib) x 3 micros (s).
// A triple-buffered via LDS (lead 2 micros, buf = s); B double-buffered (staged at s0,
// lead ~3 micros); s served by +16B shift on the ds_read.
// Per-wave VMEM FIFO: [s0: A(3), B(5)][s1: A(3)][s2: A(3)] -> entry waits:
//   s0: vmcnt(3); s1: vmcnt(8) (tail m=17: 3); s2: vmcnt(8) (tail: 0).
// Per micro: entry wait+BAR, then 4 phases {reads; [stage]; BAR; prio1 12 MFMA prio0}:
//   P1: af0-5,bv0,bv1 + stageA(u+2) | P2: bv2,bv3 | P3: bv4,bv5 + stageB(m+1)@s0 | P4: bv6,bv7
template<int MODE>
__global__ __launch_bounds__(256, 2)
void k_conv(const bf16* __restrict__ wre, const bf16* __restrict__ inpack,
            const float* __restrict__ bias_g, const bf16* __restrict__ respack,
            bf16* __restrict__ outpack, float* __restrict__ outp) {
  const int tid  = threadIdx.x;
  const int lane = tid & 63;
  const int wv   = tid >> 6;          // 0..3
  const int wm   = wv >> 1;           // 0..1 (o half)
  const int wn   = wv & 1;            // 0..1 (p half = image row)
  const int l15  = lane & 15, l4 = lane >> 4;

  // XCD-aware chunked remap: 1024 blocks, 128/XCD => each XCD owns 2 batches
  const int bid  = blockIdx.x;
  const int n    = (bid & 7) * 128 + (bid >> 3);
  const int b    = n >> 6;
  const int tile = n & 63;
  const int p0   = tile * 256;
  const int h0   = tile * 2;

  __shared__ __align__(16) bf16 Alds[3][12*512];    // 36864 B
  __shared__ __align__(16) bf16 Blds[2][4*2560];    // 40960 B
  __shared__ float bias_lds[CO];

  if (tid < CO) bias_lds[tid] = (MODE == 0) ? bias_g[b*CO + tid] : bias_g[tid];

  const size_t wbase = (MODE == 0) ? ((size_t)b*CO*KTOT) : 0;

  // A staging: 12 chunks of 1KB per micro-step; wave wv stages {wv, wv+4, wv+8}
  const bf16* aS = wre + wbase + (size_t)wv*512 + lane*8;
  // B staging: wave wv stages kg=wv; 5 overlapped chunks over contiguous row-pair (4160B)
  const bf16* bbase = inpack + (((size_t)b*24 + wv)*HPHP + (size_t)h0*HP)*8 + lane*8;
  int ibm = 0; ptrdiff_t boffEl = 0;   // macro (r,ib) element offset

  auto stageA = [&](bf16* dbuf) {
    bf16* d = dbuf + wv*512;
    gll16(aS,        d);
    gll16(aS + 2048, d + 2048);
    gll16(aS + 4096, d + 4096);
    aS += 6144;
  };
  auto stageB = [&](bf16* dbuf) {
    const bf16* src = bbase + boffEl;
    bf16* d = dbuf + wv*2560;
    gll16(src,        d);
    gll16(src +  512, d +  512);
    gll16(src + 1024, d + 1024);
    gll16(src + 1536, d + 1536);
    gll16(src + 1568, d + 1568);   // overlapped tail chunk (3136..4159 B)
    if (++ibm == 6) { ibm = 0; boffEl += (ptrdiff_t)(HP - 20*HPHP)*8; }
    else boffEl += (ptrdiff_t)4*HPHP*8;
  };

  f32x4 acc[6][8];
  #pragma unroll
  for (int mf = 0; mf < 6; ++mf)
    #pragma unroll
    for (int nf = 0; nf < 8; ++nf)
      #pragma unroll
      for (int jj = 0; jj < 4; ++jj) acc[mf][nf][jj] = 0.f;

  const int sw = l15*4 + (l4 ^ ((l15 >> 1) & 3));       // swizzled A slot
  const int bvb = l4*2560 + (wn*130 + l15)*8;           // B read base (elements)

  // prologue FIFO: [A(0):3][B(0):5][A(1):3]
  stageA(Alds[0]);
  stageB(Blds[0]);
  stageA(Alds[1]);

  bf16* Bcur = (bf16*)Blds[0];
  bf16* Bnxt = (bf16*)Blds[1];

  for (int m = 0; m < 18; ++m) {
    #pragma unroll
    for (int s = 0; s < 3; ++s) {
      // ---- entry wait + barrier (FIFO-derived counted waits) ----
      if (s == 0)          asm volatile("s_waitcnt vmcnt(3)" ::: "memory");
      else if (m < 17)     asm volatile("s_waitcnt vmcnt(8)" ::: "memory");
      else if (s == 1)     asm volatile("s_waitcnt vmcnt(3)" ::: "memory");
      else                 asm volatile("s_waitcnt vmcnt(0)" ::: "memory");
      __builtin_amdgcn_s_barrier();

      const bf16* A  = Alds[s];         // u%3 == s
      const bf16* bp = Bcur + bvb + s*8;

      // ---- P1: af0-5 + bv0,bv1 ; stageA(u+2) ; 12 MFMA ----
      bf16x8 af0 = *(const bf16x8*)(A + (wm*6 + 0)*512 + sw*8);
      bf16x8 af1 = *(const bf16x8*)(A + (wm*6 + 1)*512 + sw*8);
      bf16x8 af2 = *(const bf16x8*)(A + (wm*6 + 2)*512 + sw*8);
      bf16x8 af3 = *(const bf16x8*)(A + (wm*6 + 3)*512 + sw*8);
      bf16x8 af4 = *(const bf16x8*)(A + (wm*6 + 4)*512 + sw*8);
      bf16x8 af5 = *(const bf16x8*)(A + (wm*6 + 5)*512 + sw*8);
      bf16x8 bv0 = *(const bf16x8*)(bp);
      bf16x8 bv1 = *(const bf16x8*)(bp + 128);

      if (3*m + s + 2 < NT) stageA(Alds[(s+2)%3]);     // A(u+2)

      __builtin_amdgcn_s_barrier();
      __builtin_amdgcn_s_setprio(1);
      acc[0][0] = __builtin_amdgcn_mfma_f32_16x16x32_bf16(af0, bv0, acc[0][0], 0, 0, 0);
      acc[1][0] = __builtin_amdgcn_mfma_f32_16x16x32_bf16(af1, bv0, acc[1][0], 0, 0, 0);
      acc[2][0] = __builtin_amdgcn_mfma_f32_16x16x32_bf16(af2, bv0, acc[2][0], 0, 0, 0);
      acc[3][0] = __builtin_amdgcn_mfma_f32_16x16x32_bf16(af3, bv0, acc[3][0], 0, 0, 0);
      acc[4][0] = __builtin_amdgcn_mfma_f32_16x16x32_bf16(af4, bv0, acc[4][0], 0, 0, 0);
      acc[5][0] = __builtin_amdgcn_mfma_f32_16x16x32_bf16(af5, bv0, acc[5][0], 0, 0, 0);
      acc[0][1] = __builtin_amdgcn_mfma_f32_16x16x32_bf16(af0, bv1, acc[0][1], 0, 0, 0);
      acc[1][1] = __builtin_amdgcn_mfma_f32_16x16x32_bf16(af1, bv1, acc[1][1], 0, 0, 0);
      acc[2][1] = __builtin_amdgcn_mfma_f32_16x16x32_bf16(af2, bv1, acc[2][1], 0, 0, 0);
      acc[3][1] = __builtin_amdgcn_mfma_f32_16x16x32_bf16(af3, bv1, acc[3][1], 0, 0, 0);
      acc[4][1] = __builtin_amdgcn_mfma_f32_16x16x32_bf16(af4, bv1, acc[4][1], 0, 0, 0);
      acc[5][1] = __builtin_amdgcn_mfma_f32_16x16x32_bf16(af5, bv1, acc[5][1], 0, 0, 0);
      __builtin_amdgcn_s_setprio(0);

      // ---- P2: bv2,bv3 ; 12 MFMA ----
      bf16x8 bv2 = *(const bf16x8*)(bp + 256);
      bf16x8 bv3 = *(const bf16x8*)(bp + 384);
      __builtin_amdgcn_s_barrier();
      __builtin_amdgcn_s_setprio(1);
      acc[0][2] = __builtin_amdgcn_mfma_f32_16x16x32_bf16(af0, bv2, acc[0][2], 0, 0, 0);
      acc[1][2] = __builtin_amdgcn_mfma_f32_16x16x32_bf16(af1, bv2, acc[1][2], 0, 0, 0);
      acc[2][2] = __builtin_amdgcn_mfma_f32_16x16x32_bf16(af2, bv2, acc[2][2], 0, 0, 0);
      acc[3][2] = __builtin_amdgcn_mfma_f32_16x16x32_bf16(af3, bv2, acc[3][2], 0, 0, 0);
      acc[4][2] = __builtin_amdgcn_mfma_f32_16x16x32_bf16(af4, bv2, acc[4][2], 0, 0, 0);
      acc[5][2] = __builtin_amdgcn_mfma_f32_16x16x32_bf16(af5, bv2, acc[5][2], 0, 0, 0);
      acc[0][3] = __builtin_amdgcn_mfma_f32_16x16x32_bf16(af0, bv3, acc[0][3], 0, 0, 0);
      acc[1][3] = __builtin_amdgcn_mfma_f32_16x16x32_bf16(af1, bv3, acc[1][3], 0, 0, 0);
      acc[2][3] = __builtin_amdgcn_mfma_f32_16x16x32_bf16(af2, bv3, acc[2][3], 0, 0, 0);
      acc[3][3] = __builtin_amdgcn_mfma_f32_16x16x32_bf16(af3, bv3, acc[3][3], 0, 0, 0);
      acc[4][3] = __builtin_amdgcn_mfma_f32_16x16x32_bf16(af4, bv3, acc[4][3], 0, 0, 0);
      acc[5][3] = __builtin_amdgcn_mfma_f32_16x16x32_bf16(af5, bv3, acc[5][3], 0, 0, 0);
      __builtin_amdgcn_s_setprio(0);

      // ---- P3: bv4,bv5 ; stageB(m+1) at s0 ; 12 MFMA ----
      bf16x8 bv4 = *(const bf16x8*)(bp + 512);
      bf16x8 bv5 = *(const bf16x8*)(bp + 640);
      if (s == 0 && m < 17) stageB(Bnxt);              // B(m+1), ~3-micro lead
      __builtin_amdgcn_s_barrier();
      __builtin_amdgcn_s_setprio(1);
      acc[0][4] = __builtin_amdgcn_mfma_f32_16x16x32_bf16(af0, bv4, acc[0][4], 0, 0, 0);
      acc[1][4] = __builtin_amdgcn_mfma_f32_16x16x32_bf16(af1, bv4, acc[1][4], 0, 0, 0);
      acc[2][4] = __builtin_amdgcn_mfma_f32_16x16x32_bf16(af2, bv4, acc[2][4], 0, 0, 0);
      acc[3][4] = __builtin_amdgcn_mfma_f32_16x16x32_bf16(af3, bv4, acc[3][4], 0, 0, 0);
      acc[4][4] = __builtin_amdgcn_mfma_f32_16x16x32_bf16(af4, bv4, acc[4][4], 0, 0, 0);
      acc[5][4] = __builtin_amdgcn_mfma_f32_16x16x32_bf16(af5, bv4, acc[5][4], 0, 0, 0);
      acc[0][5] = __builtin_amdgcn_mfma_f32_16x16x32_bf16(af0, bv5, acc[0][5], 0, 0, 0);
      acc[1][5] = __builtin_amdgcn_mfma_f32_16x16x32_bf16(af1, bv5, acc[1][5], 0, 0, 0);
      acc[2][5] = __builtin_amdgcn_mfma_f32_16x16x32_bf16(af2, bv5, acc[2][5], 0, 0, 0);
      acc[3][5] = __builtin_amdgcn_mfma_f32_16x16x32_bf16(af3, bv5, acc[3][5], 0, 0, 0);
      acc[4][5] = __builtin_amdgcn_mfma_f32_16x16x32_bf16(af4, bv5, acc[4][5], 0, 0, 0);
      acc[5][5] = __builtin_amdgcn_mfma_f32_16x16x32_bf16(af5, bv5, acc[5][5], 0, 0, 0);
      __builtin_amdgcn_s_setprio(0);

      // ---- P4: bv6,bv7 ; 12 MFMA ----
      bf16x8 bv6 = *(const bf16x8*)(bp + 768);
      bf16x8 bv7 = *(const bf16x8*)(bp + 896);
      __builtin_amdgcn_s_barrier();
      __builtin_amdgcn_s_setprio(1);
      acc[0][6] = __builtin_amdgcn_mfma_f32_16x16x32_bf16(af0, bv6, acc[0][6], 0, 0, 0);
      acc[1][6] = __builtin_amdgcn_mfma_f32_16x16x32_bf16(af1, bv6, acc[1][6], 0, 0, 0);
      acc[2][6] = __builtin_amdgcn_mfma_f32_16x16x32_bf16(af2, bv6, acc[2][6], 0, 0, 0);
      acc[3][6] = __builtin_amdgcn_mfma_f32_16x16x32_bf16(af3, bv6, acc[3][6], 0, 0, 0);
      acc[4][6] = __builtin_amdgcn_mfma_f32_16x16x32_bf16(af4, bv6, acc[4][6], 0, 0, 0);
      acc[5][6] = __builtin_amdgcn_mfma_f32_16x16x32_bf16(af5, bv6, acc[5][6], 0, 0, 0);
      acc[0][7] = __builtin_amdgcn_mfma_f32_16x16x32_bf16(af0, bv7, acc[0][7], 0, 0, 0);
      acc[1][7] = __builtin_amdgcn_mfma_f32_16x16x32_bf16(af1, bv7, acc[1][7], 0, 0, 0);
      acc[2][7] = __builtin_amdgcn_mfma_f32_16x16x32_bf16(af2, bv7, acc[2][7], 0, 0, 0);
      acc[3][7] = __builtin_amdgcn_mfma_f32_16x16x32_bf16(af3, bv7, acc[3][7], 0, 0, 0);
      acc[4][7] = __builtin_amdgcn_mfma_f32_16x16x32_bf16(af4, bv7, acc[4][7], 0, 0, 0);
      acc[5][7] = __builtin_amdgcn_mfma_f32_16x16x32_bf16(af5, bv7, acc[5][7], 0, 0, 0);
      __builtin_amdgcn_s_setprio(0);
    }
    { bf16* t = Bcur; Bcur = Bnxt; Bnxt = t; }
  }

  // epilogue
  #pragma unroll
  for (int mf = 0; mf < 6; ++mf) {
    int ob = wm*96 + mf*16 + l4*4;     // output channel base (4 consecutive)
    #pragma unroll
    for (int nf = 0; nf < 8; ++nf) {
      int pl = wn*128 + nf*16 + l15;
      int p  = p0 + pl;
      f32x4 v = acc[mf][nf];
      int h = p >> 7, w = p & 127;
      size_t basep = (((size_t)b*24 + (ob >> 3))*HP + (h + 1))*HP + (w + 1);
      if (MODE == 0) {
        bf16x4 pk;
        #pragma unroll
        for (int jj = 0; jj < 4; ++jj) {
          float xv = v[jj] + bias_lds[ob + jj];
          pk[jj] = (bf16)silu_f(xv);
        }
        *(bf16x4*)(outpack + basep*8 + (ob & 7)) = pk;
      } else {
        bf16x4 rr = *(const bf16x4*)(respack + basep*8 + (ob & 7));
        #pragma unroll
        for (int jj = 0; jj < 4; ++jj) {
          float xv = silu_f(v[jj] + bias_lds[ob + jj]);
          size_t idx = ((size_t)b*CO + ob + jj)*NPX + p;
          outp[idx] = xv + (float)rr[jj];
        }
      }
    }
  }
}

extern "C" void kernel_launch(void* const* d_in, const int* in_sizes, int n_in,
                              void* d_out, int out_size, void* d_ws, size_t ws_size,
                              hipStream_t stream) {
  const float* x        = (const float*)d_in[0];
  const float* latent   = (const float*)d_in[1];
  const float* expert_w = (const float*)d_in[2];
  const float* expert_b = (const float*)d_in[3];
  const float* attn_w   = (const float*)d_in[4];
  const float* attn_b   = (const float*)d_in[5];
  const float* conv2_w  = (const float*)d_in[6];
  const float* conv2_b  = (const float*)d_in[7];
  float* outp = (float*)d_out;

  char* base = (char*)d_ws;
  size_t off = 0;
  float* attn = (float*)(base + off); off += 4096;
  float* bdyn = (float*)(base + off); off += 16384;
  bf16* w_re  = (bf16*)(base + off);  off += (size_t)B_*CO*KTOT*2;      // 10.6 MB
  bf16* w2_re = (bf16*)(base + off);  off += (size_t)CO*KTOT*2;         // 0.66 MB
  bf16* xpack = (bf16*)(base + off);  off += (size_t)B_*24*HPHP*8*2;    // 103.8 MB
  bf16* midpack = (bf16*)(base + off); off += (size_t)B_*24*HPHP*8*2;   // 103.8 MB
  (void)ws_size; (void)in_sizes; (void)n_in; (void)out_size;

  k_attn<<<dim3(1), dim3(128), 0, stream>>>(latent, attn_w, attn_b, attn);
  k_bdyn<<<dim3(12), dim3(256), 0, stream>>>(attn, expert_b, bdyn);
  k_wdyn<<<dim3(CO), dim3(256), 0, stream>>>(expert_w, attn, w_re);
  k_w2re<<<dim3(CO), dim3(256), 0, stream>>>(conv2_w, w2_re);
  k_xpack<<<dim3(130, 24, 16), dim3(128), 0, stream>>>(x, xpack);
  k_midborder<<<dim3(B_*24), dim3(256), 0, stream>>>(midpack);
  k_conv<0><<<dim3(1024), dim3(256), 0, stream>>>(w_re, xpack, bdyn, xpack, midpack, outp);
  k_conv<1><<<dim3(1024), dim3(256), 0, stream>>>(w2_re, midpack, conv2_b, xpack, midpack, outp);
}

// Round 12
// 485.908 us; speedup vs baseline: 1.1183x; 1.0305x over previous
//
#include <hip/hip_runtime.h>
#include <stdint.h>
#include <stddef.h>

typedef __bf16 bf16;
typedef bf16 bf16x8 __attribute__((ext_vector_type(8)));
typedef bf16 bf16x4 __attribute__((ext_vector_type(4)));
typedef float f32x4 __attribute__((ext_vector_type(4)));

#define B_   16
#define CI   192
#define CO   192
#define H_   128
#define W_   128
#define KE   8
#define LD   64
#define KTOT 1728   // 9*192
#define HP   130    // padded H/W
#define HPHP (HP*HP)
#define NPX  (H_*W_)
#define NT   54     // K micro-steps of 32 (order: r-major, ib, s-minor)

__device__ __forceinline__ void gll16(const void* g, void* l) {
  __builtin_amdgcn_global_load_lds(
      (const __attribute__((address_space(1))) unsigned int*)g,
      (__attribute__((address_space(3))) unsigned int*)l, 16, 0, 0);
}

__device__ __forceinline__ float silu_f(float x) {
  return x / (1.f + __expf(-x));
}

// ---------------- attention softmax: latent[16,64] -> attn[16,8] ----------------
__global__ void k_attn(const float* __restrict__ latent, const float* __restrict__ attn_w,
                       const float* __restrict__ attn_b, float* __restrict__ attn) {
  int t = threadIdx.x;           // 128 threads: b = t>>3, k = t&7
  int b = t >> 3, k = t & 7;
  float s = attn_b[k];
  for (int d = 0; d < LD; ++d) s += latent[b*LD + d] * attn_w[k*LD + d];
  float m = s;
  for (int off = 4; off; off >>= 1) m = fmaxf(m, __shfl_xor(m, off, 8));
  float e = __expf(s - m);
  float sum = e;
  for (int off = 4; off; off >>= 1) sum += __shfl_xor(sum, off, 8);
  attn[t] = e / sum;
}

// ---------------- dynamic bias ----------------
__global__ void k_bdyn(const float* __restrict__ attn, const float* __restrict__ expert_b,
                       float* __restrict__ bdyn) {
  int j = blockIdx.x * 256 + threadIdx.x;
  if (j >= B_ * CO) return;
  int b = j / CO, o = j - b * CO;
  float s = 0.f;
  #pragma unroll
  for (int e = 0; e < KE; ++e) s += attn[b*KE + e] * expert_b[e*CO + o];
  bdyn[j] = s;
}

// ---------------- dynamic weights -> staged layout [b][kt=54][chunk=12][slot=64][8] bf16
// K order: kt = r*18 + ib*3 + s  (s innermost). slot L holds (row=L>>2, ks=(L&3)^((row>>1)&3)).
// element: o = chunk*16+row, i = ib*32 + ks*8 + j, weight (o, i, r, s).
__global__ void k_wdyn(const float* __restrict__ expert_w, const float* __restrict__ attn,
                       bf16* __restrict__ w_re) {
  int o = blockIdx.x;            // 192
  int chunk = o >> 4, row = o & 15, c = (row >> 1) & 3;
  __shared__ float ew[KE][KTOT];
  __shared__ float al[B_][KE];
  for (int e = 0; e < KE; ++e)
    for (int j = threadIdx.x; j < KTOT; j += 256)
      ew[e][j] = expert_w[((size_t)e*CO + o)*KTOT + j];   // [i*9+rs]
  if (threadIdx.x < B_*KE) al[threadIdx.x >> 3][threadIdx.x & 7] = attn[threadIdx.x];
  __syncthreads();
  for (int idx = threadIdx.x; idx < B_*KTOT; idx += 256) {
    int b = idx / KTOT, k = idx - b*KTOT;
    int kt = k >> 5, ks = (k >> 3) & 3, j = k & 7;
    int r = kt / 18, t2 = kt - r*18;
    int ibb = t2 / 3, s = t2 - ibb*3;
    int i = ibb*32 + ks*8 + j;
    float acc = 0.f;
    #pragma unroll
    for (int e = 0; e < KE; ++e) acc += al[b][e] * ew[e][i*9 + r*3 + s];
    int slot = row*4 + (ks ^ c);
    w_re[((((size_t)b*NT + kt)*12 + chunk)*64 + slot)*8 + j] = (bf16)acc;
  }
}

// ---------------- static conv2 weights -> same staged layout (no b) ----------------
__global__ void k_w2re(const float* __restrict__ conv2_w, bf16* __restrict__ w2_re) {
  int o = blockIdx.x;
  int chunk = o >> 4, row = o & 15, c = (row >> 1) & 3;
  __shared__ float cw[KTOT];
  for (int j = threadIdx.x; j < KTOT; j += 256) cw[j] = conv2_w[(size_t)o*KTOT + j];
  __syncthreads();
  for (int k = threadIdx.x; k < KTOT; k += 256) {
    int kt = k >> 5, ks = (k >> 3) & 3, j = k & 7;
    int r = kt / 18, t2 = kt - r*18;
    int ibb = t2 / 3, s = t2 - ibb*3;
    int i = ibb*32 + ks*8 + j;
    int slot = row*4 + (ks ^ c);
    w2_re[(((size_t)kt*12 + chunk)*64 + slot)*8 + j] = (bf16)cw[i*9 + r*3 + s];
  }
}

// ---------------- pack+pad x: f32 NCHW -> bf16 [b][i/8][130][130][8], zero borders ----------------
__global__ void k_xpack(const float* __restrict__ x, bf16* __restrict__ xpack) {
  int h2 = blockIdx.x, ib = blockIdx.y, b = blockIdx.z;
  size_t rowbase = (((size_t)b*24 + ib)*HP + h2)*HP;
  int t = threadIdx.x;  // 128
  if (h2 == 0 || h2 == HP-1) {
    uint4 z = make_uint4(0,0,0,0);
    for (int w = t; w < HP; w += 128) *(uint4*)(xpack + (rowbase + w)*8) = z;
    return;
  }
  __shared__ float tt[8][128];
  int h = h2 - 1;
  #pragma unroll
  for (int ii = 0; ii < 8; ++ii)
    tt[ii][t] = x[(((size_t)b*CI + ib*8 + ii)*H_ + h)*W_ + t];
  __syncthreads();
  bf16x8 v;
  #pragma unroll
  for (int ii = 0; ii < 8; ++ii) v[ii] = (bf16)tt[ii][t];
  *(bf16x8*)(xpack + (rowbase + t + 1)*8) = v;
  if (t == 0) {
    uint4 z = make_uint4(0,0,0,0);
    *(uint4*)(xpack + rowbase*8) = z;
    *(uint4*)(xpack + (rowbase + HP-1)*8) = z;
  }
}

// ---------------- zero borders of midpack ----------------
__global__ void k_midborder(bf16* __restrict__ midpack) {
  int bi = blockIdx.x;  // b*24+ib
  size_t base = (size_t)bi * HPHP;
  uint4 z = make_uint4(0,0,0,0);
  for (int j = threadIdx.x; j < 516; j += 256) {
    int h2, w2;
    if (j < 130)      { h2 = 0;       w2 = j; }
    else if (j < 260) { h2 = 129;     w2 = j - 130; }
    else if (j < 388) { h2 = j - 259; w2 = 0; }
    else              { h2 = j - 387; w2 = 129; }
    *(uint4*)(midpack + (base + (size_t)h2*HP + w2)*8) = z;
  }
}

// ---------------- implicit-GEMM 3x3 conv, BM=192 x BN=256(2 rows), K order (r,ib,s) ----------------
// Proven R8 pipeline (214us/conv): 2-phase micro, counted-vmcnt, T5 setprio.
// 4 waves (2m x 2n), per-wave 96x128. 18 macros (r,ib) x 3 micros (s).
// B staged once per macro; s served by +16B shift on the LDS read. A triple-buffered
// (lead 2 micros, buf = s), B double-buffered (lead 3 micros).
// Prologue FIFO fixed to [B0, A0, A1] so first s0 entry vmcnt(3) provably drains B0+A0
// (keeps only A1) — closes R8's latent first-iteration race. Steady-state unchanged:
//   s0/s1 entry vmcnt(3): drains A(u), keeps A(u+1) [+B in s2 case]
//   s2 entry vmcnt(8): drains A(u), keeps A(u+1)+B(m+1); tail m=17: vmcnt(0).
// Per micro: entry wait + BAR;
//   P1: ds_read af0-5,bv0-3 ; issue A(u+2) ; BAR ; prio1 24 MFMA(nf0-3) prio0
//   P2: ds_read bv4-7       ; issue B(m+1) at s1 ; BAR ; prio1 24 MFMA(nf4-7) prio0
template<int MODE>
__global__ __launch_bounds__(256, 2)
void k_conv(const bf16* __restrict__ wre, const bf16* __restrict__ inpack,
            const float* __restrict__ bias_g, const bf16* __restrict__ respack,
            bf16* __restrict__ outpack, float* __restrict__ outp) {
  const int tid  = threadIdx.x;
  const int lane = tid & 63;
  const int wv   = tid >> 6;          // 0..3
  const int wm   = wv >> 1;           // 0..1 (o half)
  const int wn   = wv & 1;            // 0..1 (p half = image row)
  const int l15  = lane & 15, l4 = lane >> 4;

  // XCD-aware chunked remap: 1024 blocks, 128/XCD => each XCD owns 2 batches
  const int bid  = blockIdx.x;
  const int n    = (bid & 7) * 128 + (bid >> 3);
  const int b    = n >> 6;
  const int tile = n & 63;
  const int p0   = tile * 256;
  const int h0   = tile * 2;

  __shared__ __align__(16) bf16 Alds[3][12*512];    // 36864 B
  __shared__ __align__(16) bf16 Blds[2][4*2560];    // 40960 B
  __shared__ float bias_lds[CO];

  if (tid < CO) bias_lds[tid] = (MODE == 0) ? bias_g[b*CO + tid] : bias_g[tid];

  const size_t wbase = (MODE == 0) ? ((size_t)b*CO*KTOT) : 0;

  // A staging: 12 chunks of 1KB per micro-step; wave wv stages {wv, wv+4, wv+8}
  const bf16* aS = wre + wbase + (size_t)wv*512 + lane*8;
  // B staging: wave wv stages kg=wv; 5 overlapped chunks over contiguous row-pair (4160B)
  const bf16* bbase = inpack + (((size_t)b*24 + wv)*HPHP + (size_t)h0*HP)*8 + lane*8;
  int ibm = 0; ptrdiff_t boffEl = 0;   // macro (r,ib) element offset

  auto stageA = [&](bf16* dbuf) {
    bf16* d = dbuf + wv*512;
    gll16(aS,        d);
    gll16(aS + 2048, d + 2048);
    gll16(aS + 4096, d + 4096);
    aS += 6144;
  };
  auto stageB = [&](bf16* dbuf) {
    const bf16* src = bbase + boffEl;
    bf16* d = dbuf + wv*2560;
    gll16(src,        d);
    gll16(src +  512, d +  512);
    gll16(src + 1024, d + 1024);
    gll16(src + 1536, d + 1536);
    gll16(src + 1568, d + 1568);   // overlapped tail chunk (3136..4159 B)
    if (++ibm == 6) { ibm = 0; boffEl += (ptrdiff_t)(HP - 20*HPHP)*8; }
    else boffEl += (ptrdiff_t)4*HPHP*8;
  };

  f32x4 acc[6][8];
  #pragma unroll
  for (int mf = 0; mf < 6; ++mf)
    #pragma unroll
    for (int nf = 0; nf < 8; ++nf)
      #pragma unroll
      for (int jj = 0; jj < 4; ++jj) acc[mf][nf][jj] = 0.f;

  const int sw = l15*4 + (l4 ^ ((l15 >> 1) & 3));       // swizzled A slot
  const int bvb = l4*2560 + (wn*130 + l15)*8;           // B read base (elements)

  // prologue FIFO: [B(0):5][A(0):3][A(1):3] — first entry vmcnt(3) drains B0+A0, keeps A1
  stageB(Blds[0]);
  stageA(Alds[0]);
  stageA(Alds[1]);

  bf16* Bcur = (bf16*)Blds[0];
  bf16* Bnxt = (bf16*)Blds[1];

  for (int m = 0; m < 18; ++m) {
    #pragma unroll
    for (int s = 0; s < 3; ++s) {
      // ---- entry wait + barrier (counted schedule) ----
      if (s == 2) {
        if (m == 17) asm volatile("s_waitcnt vmcnt(0)" ::: "memory");
        else         asm volatile("s_waitcnt vmcnt(8)" ::: "memory");
      } else {
        asm volatile("s_waitcnt vmcnt(3)" ::: "memory");
      }
      __builtin_amdgcn_s_barrier();

      const bf16* A = Alds[s];          // u%3 == s
      const bf16* bp = Bcur + bvb + s*8;

      // ---- P1: reads + A-stage, then 24 MFMA (nf 0-3) ----
      bf16x8 af0 = *(const bf16x8*)(A + (wm*6 + 0)*512 + sw*8);
      bf16x8 af1 = *(const bf16x8*)(A + (wm*6 + 1)*512 + sw*8);
      bf16x8 af2 = *(const bf16x8*)(A + (wm*6 + 2)*512 + sw*8);
      bf16x8 af3 = *(const bf16x8*)(A + (wm*6 + 3)*512 + sw*8);
      bf16x8 af4 = *(const bf16x8*)(A + (wm*6 + 4)*512 + sw*8);
      bf16x8 af5 = *(const bf16x8*)(A + (wm*6 + 5)*512 + sw*8);
      bf16x8 bv0 = *(const bf16x8*)(bp);
      bf16x8 bv1 = *(const bf16x8*)(bp + 128);
      bf16x8 bv2 = *(const bf16x8*)(bp + 256);
      bf16x8 bv3 = *(const bf16x8*)(bp + 384);

      if (3*m + s + 2 < NT) stageA(Alds[(s+2)%3]);     // A(u+2)

      __builtin_amdgcn_s_barrier();
      __builtin_amdgcn_s_setprio(1);
      acc[0][0] = __builtin_amdgcn_mfma_f32_16x16x32_bf16(af0, bv0, acc[0][0], 0, 0, 0);
      acc[1][0] = __builtin_amdgcn_mfma_f32_16x16x32_bf16(af1, bv0, acc[1][0], 0, 0, 0);
      acc[2][0] = __builtin_amdgcn_mfma_f32_16x16x32_bf16(af2, bv0, acc[2][0], 0, 0, 0);
      acc[3][0] = __builtin_amdgcn_mfma_f32_16x16x32_bf16(af3, bv0, acc[3][0], 0, 0, 0);
      acc[4][0] = __builtin_amdgcn_mfma_f32_16x16x32_bf16(af4, bv0, acc[4][0], 0, 0, 0);
      acc[5][0] = __builtin_amdgcn_mfma_f32_16x16x32_bf16(af5, bv0, acc[5][0], 0, 0, 0);
      acc[0][1] = __builtin_amdgcn_mfma_f32_16x16x32_bf16(af0, bv1, acc[0][1], 0, 0, 0);
      acc[1][1] = __builtin_amdgcn_mfma_f32_16x16x32_bf16(af1, bv1, acc[1][1], 0, 0, 0);
      acc[2][1] = __builtin_amdgcn_mfma_f32_16x16x32_bf16(af2, bv1, acc[2][1], 0, 0, 0);
      acc[3][1] = __builtin_amdgcn_mfma_f32_16x16x32_bf16(af3, bv1, acc[3][1], 0, 0, 0);
      acc[4][1] = __builtin_amdgcn_mfma_f32_16x16x32_bf16(af4, bv1, acc[4][1], 0, 0, 0);
      acc[5][1] = __builtin_amdgcn_mfma_f32_16x16x32_bf16(af5, bv1, acc[5][1], 0, 0, 0);
      acc[0][2] = __builtin_amdgcn_mfma_f32_16x16x32_bf16(af0, bv2, acc[0][2], 0, 0, 0);
      acc[1][2] = __builtin_amdgcn_mfma_f32_16x16x32_bf16(af1, bv2, acc[1][2], 0, 0, 0);
      acc[2][2] = __builtin_amdgcn_mfma_f32_16x16x32_bf16(af2, bv2, acc[2][2], 0, 0, 0);
      acc[3][2] = __builtin_amdgcn_mfma_f32_16x16x32_bf16(af3, bv2, acc[3][2], 0, 0, 0);
      acc[4][2] = __builtin_amdgcn_mfma_f32_16x16x32_bf16(af4, bv2, acc[4][2], 0, 0, 0);
      acc[5][2] = __builtin_amdgcn_mfma_f32_16x16x32_bf16(af5, bv2, acc[5][2], 0, 0, 0);
      acc[0][3] = __builtin_amdgcn_mfma_f32_16x16x32_bf16(af0, bv3, acc[0][3], 0, 0, 0);
      acc[1][3] = __builtin_amdgcn_mfma_f32_16x16x32_bf16(af1, bv3, acc[1][3], 0, 0, 0);
      acc[2][3] = __builtin_amdgcn_mfma_f32_16x16x32_bf16(af2, bv3, acc[2][3], 0, 0, 0);
      acc[3][3] = __builtin_amdgcn_mfma_f32_16x16x32_bf16(af3, bv3, acc[3][3], 0, 0, 0);
      acc[4][3] = __builtin_amdgcn_mfma_f32_16x16x32_bf16(af4, bv3, acc[4][3], 0, 0, 0);
      acc[5][3] = __builtin_amdgcn_mfma_f32_16x16x32_bf16(af5, bv3, acc[5][3], 0, 0, 0);
      __builtin_amdgcn_s_setprio(0);

      // ---- P2: reads + B-stage, then 24 MFMA (nf 4-7) ----
      bf16x8 bv4 = *(const bf16x8*)(bp + 512);
      bf16x8 bv5 = *(const bf16x8*)(bp + 640);
      bf16x8 bv6 = *(const bf16x8*)(bp + 768);
      bf16x8 bv7 = *(const bf16x8*)(bp + 896);

      if (s == 1 && m < 17) stageB(Bnxt);              // B(m+1)

      __builtin_amdgcn_s_barrier();
      __builtin_amdgcn_s_setprio(1);
      acc[0][4] = __builtin_amdgcn_mfma_f32_16x16x32_bf16(af0, bv4, acc[0][4], 0, 0, 0);
      acc[1][4] = __builtin_amdgcn_mfma_f32_16x16x32_bf16(af1, bv4, acc[1][4], 0, 0, 0);
      acc[2][4] = __builtin_amdgcn_mfma_f32_16x16x32_bf16(af2, bv4, acc[2][4], 0, 0, 0);
      acc[3][4] = __builtin_amdgcn_mfma_f32_16x16x32_bf16(af3, bv4, acc[3][4], 0, 0, 0);
      acc[4][4] = __builtin_amdgcn_mfma_f32_16x16x32_bf16(af4, bv4, acc[4][4], 0, 0, 0);
      acc[5][4] = __builtin_amdgcn_mfma_f32_16x16x32_bf16(af5, bv4, acc[5][4], 0, 0, 0);
      acc[0][5] = __builtin_amdgcn_mfma_f32_16x16x32_bf16(af0, bv5, acc[0][5], 0, 0, 0);
      acc[1][5] = __builtin_amdgcn_mfma_f32_16x16x32_bf16(af1, bv5, acc[1][5], 0, 0, 0);
      acc[2][5] = __builtin_amdgcn_mfma_f32_16x16x32_bf16(af2, bv5, acc[2][5], 0, 0, 0);
      acc[3][5] = __builtin_amdgcn_mfma_f32_16x16x32_bf16(af3, bv5, acc[3][5], 0, 0, 0);
      acc[4][5] = __builtin_amdgcn_mfma_f32_16x16x32_bf16(af4, bv5, acc[4][5], 0, 0, 0);
      acc[5][5] = __builtin_amdgcn_mfma_f32_16x16x32_bf16(af5, bv5, acc[5][5], 0, 0, 0);
      acc[0][6] = __builtin_amdgcn_mfma_f32_16x16x32_bf16(af0, bv6, acc[0][6], 0, 0, 0);
      acc[1][6] = __builtin_amdgcn_mfma_f32_16x16x32_bf16(af1, bv6, acc[1][6], 0, 0, 0);
      acc[2][6] = __builtin_amdgcn_mfma_f32_16x16x32_bf16(af2, bv6, acc[2][6], 0, 0, 0);
      acc[3][6] = __builtin_amdgcn_mfma_f32_16x16x32_bf16(af3, bv6, acc[3][6], 0, 0, 0);
      acc[4][6] = __builtin_amdgcn_mfma_f32_16x16x32_bf16(af4, bv6, acc[4][6], 0, 0, 0);
      acc[5][6] = __builtin_amdgcn_mfma_f32_16x16x32_bf16(af5, bv6, acc[5][6], 0, 0, 0);
      acc[0][7] = __builtin_amdgcn_mfma_f32_16x16x32_bf16(af0, bv7, acc[0][7], 0, 0, 0);
      acc[1][7] = __builtin_amdgcn_mfma_f32_16x16x32_bf16(af1, bv7, acc[1][7], 0, 0, 0);
      acc[2][7] = __builtin_amdgcn_mfma_f32_16x16x32_bf16(af2, bv7, acc[2][7], 0, 0, 0);
      acc[3][7] = __builtin_amdgcn_mfma_f32_16x16x32_bf16(af3, bv7, acc[3][7], 0, 0, 0);
      acc[4][7] = __builtin_amdgcn_mfma_f32_16x16x32_bf16(af4, bv7, acc[4][7], 0, 0, 0);
      acc[5][7] = __builtin_amdgcn_mfma_f32_16x16x32_bf16(af5, bv7, acc[5][7], 0, 0, 0);
      __builtin_amdgcn_s_setprio(0);
    }
    { bf16* t = Bcur; Bcur = Bnxt; Bnxt = t; }
  }

  // epilogue
  #pragma unroll
  for (int mf = 0; mf < 6; ++mf) {
    int ob = wm*96 + mf*16 + l4*4;     // output channel base (4 consecutive)
    #pragma unroll
    for (int nf = 0; nf < 8; ++nf) {
      int pl = wn*128 + nf*16 + l15;
      int p  = p0 + pl;
      f32x4 v = acc[mf][nf];
      int h = p >> 7, w = p & 127;
      size_t basep = (((size_t)b*24 + (ob >> 3))*HP + (h + 1))*HP + (w + 1);
      if (MODE == 0) {
        bf16x4 pk;
        #pragma unroll
        for (int jj = 0; jj < 4; ++jj) {
          float xv = v[jj] + bias_lds[ob + jj];
          pk[jj] = (bf16)silu_f(xv);
        }
        *(bf16x4*)(outpack + basep*8 + (ob & 7)) = pk;
      } else {
        bf16x4 rr = *(const bf16x4*)(respack + basep*8 + (ob & 7));
        #pragma unroll
        for (int jj = 0; jj < 4; ++jj) {
          float xv = silu_f(v[jj] + bias_lds[ob + jj]);
          size_t idx = ((size_t)b*CO + ob + jj)*NPX + p;
          outp[idx] = xv + (float)rr[jj];
        }
      }
    }
  }
}

extern "C" void kernel_launch(void* const* d_in, const int* in_sizes, int n_in,
                              void* d_out, int out_size, void* d_ws, size_t ws_size,
                              hipStream_t stream) {
  const float* x        = (const float*)d_in[0];
  const float* latent   = (const float*)d_in[1];
  const float* expert_w = (const float*)d_in[2];
  const float* expert_b = (const float*)d_in[3];
  const float* attn_w   = (const float*)d_in[4];
  const float* attn_b   = (const float*)d_in[5];
  const float* conv2_w  = (const float*)d_in[6];
  const float* conv2_b  = (const float*)d_in[7];
  float* outp = (float*)d_out;

  char* base = (char*)d_ws;
  size_t off = 0;
  float* attn = (float*)(base + off); off += 4096;
  float* bdyn = (float*)(base + off); off += 16384;
  bf16* w_re  = (bf16*)(base + off);  off += (size_t)B_*CO*KTOT*2;      // 10.6 MB
  bf16* w2_re = (bf16*)(base + off);  off += (size_t)CO*KTOT*2;         // 0.66 MB
  bf16* xpack = (bf16*)(base + off);  off += (size_t)B_*24*HPHP*8*2;    // 103.8 MB
  bf16* midpack = (bf16*)(base + off); off += (size_t)B_*24*HPHP*8*2;   // 103.8 MB
  (void)ws_size; (void)in_sizes; (void)n_in; (void)out_size;

  k_attn<<<dim3(1), dim3(128), 0, stream>>>(latent, attn_w, attn_b, attn);
  k_bdyn<<<dim3(12), dim3(256), 0, stream>>>(attn, expert_b, bdyn);
  k_wdyn<<<dim3(CO), dim3(256), 0, stream>>>(expert_w, attn, w_re);
  k_w2re<<<dim3(CO), dim3(256), 0, stream>>>(conv2_w, w2_re);
  k_xpack<<<dim3(130, 24, 16), dim3(128), 0, stream>>>(x, xpack);
  k_midborder<<<dim3(B_*24), dim3(256), 0, stream>>>(midpack);
  k_conv<0><<<dim3(1024), dim3(256), 0, stream>>>(w_re, xpack, bdyn, xpack, midpack, outp);
  k_conv<1><<<dim3(1024), dim3(256), 0, stream>>>(w2_re, midpack, conv2_b, xpack, midpack, outp);
}

// Round 13
// 483.079 us; speedup vs baseline: 1.1249x; 1.0059x over previous
//
#include <hip/hip_runtime.h>
#include <stdint.h>
#include <stddef.h>

typedef __bf16 bf16;
typedef bf16 bf16x8 __attribute__((ext_vector_type(8)));
typedef bf16 bf16x4 __attribute__((ext_vector_type(4)));
typedef float f32x4 __attribute__((ext_vector_type(4)));
typedef float f32x16 __attribute__((ext_vector_type(16)));

#define B_   16
#define CI   192
#define CO   192
#define H_   128
#define W_   128
#define KE   8
#define LD   64
#define KTOT 1728   // 9*192
#define HP   130    // padded H/W
#define HPHP (HP*HP)
#define NPX  (H_*W_)
#define NT   54     // K micro-steps of 32 (order: r-major, ib, s-minor)

__device__ __forceinline__ void gll16(const void* g, void* l) {
  __builtin_amdgcn_global_load_lds(
      (const __attribute__((address_space(1))) unsigned int*)g,
      (__attribute__((address_space(3))) unsigned int*)l, 16, 0, 0);
}

__device__ __forceinline__ float silu_f(float x) {
  return x / (1.f + __expf(-x));
}

// ---------------- attention softmax: latent[16,64] -> attn[16,8] ----------------
__global__ void k_attn(const float* __restrict__ latent, const float* __restrict__ attn_w,
                       const float* __restrict__ attn_b, float* __restrict__ attn) {
  int t = threadIdx.x;           // 128 threads: b = t>>3, k = t&7
  int b = t >> 3, k = t & 7;
  float s = attn_b[k];
  for (int d = 0; d < LD; ++d) s += latent[b*LD + d] * attn_w[k*LD + d];
  float m = s;
  for (int off = 4; off; off >>= 1) m = fmaxf(m, __shfl_xor(m, off, 8));
  float e = __expf(s - m);
  float sum = e;
  for (int off = 4; off; off >>= 1) sum += __shfl_xor(sum, off, 8);
  attn[t] = e / sum;
}

// ---------------- dynamic bias ----------------
__global__ void k_bdyn(const float* __restrict__ attn, const float* __restrict__ expert_b,
                       float* __restrict__ bdyn) {
  int j = blockIdx.x * 256 + threadIdx.x;
  if (j >= B_ * CO) return;
  int b = j / CO, o = j - b * CO;
  float s = 0.f;
  #pragma unroll
  for (int e = 0; e < KE; ++e) s += attn[b*KE + e] * expert_b[e*CO + o];
  bdyn[j] = s;
}

// ---------------- dynamic weights -> staged layout [b][kt=54][chunk=12][slot=64][8] bf16
// K order: kt = r*18 + ib*3 + s  (s innermost). slot L holds (row=L>>2, ks=(L&3)^((row>>1)&3)).
// element: o = chunk*16+row, i = ib*32 + ks*8 + j, weight (o, i, r, s).
__global__ void k_wdyn(const float* __restrict__ expert_w, const float* __restrict__ attn,
                       bf16* __restrict__ w_re) {
  int o = blockIdx.x;            // 192
  int chunk = o >> 4, row = o & 15, c = (row >> 1) & 3;
  __shared__ float ew[KE][KTOT];
  __shared__ float al[B_][KE];
  for (int e = 0; e < KE; ++e)
    for (int j = threadIdx.x; j < KTOT; j += 256)
      ew[e][j] = expert_w[((size_t)e*CO + o)*KTOT + j];   // [i*9+rs]
  if (threadIdx.x < B_*KE) al[threadIdx.x >> 3][threadIdx.x & 7] = attn[threadIdx.x];
  __syncthreads();
  for (int idx = threadIdx.x; idx < B_*KTOT; idx += 256) {
    int b = idx / KTOT, k = idx - b*KTOT;
    int kt = k >> 5, ks = (k >> 3) & 3, j = k & 7;
    int r = kt / 18, t2 = kt - r*18;
    int ibb = t2 / 3, s = t2 - ibb*3;
    int i = ibb*32 + ks*8 + j;
    float acc = 0.f;
    #pragma unroll
    for (int e = 0; e < KE; ++e) acc += al[b][e] * ew[e][i*9 + r*3 + s];
    int slot = row*4 + (ks ^ c);
    w_re[((((size_t)b*NT + kt)*12 + chunk)*64 + slot)*8 + j] = (bf16)acc;
  }
}

// ---------------- static conv2 weights -> same staged layout (no b) ----------------
__global__ void k_w2re(const float* __restrict__ conv2_w, bf16* __restrict__ w2_re) {
  int o = blockIdx.x;
  int chunk = o >> 4, row = o & 15, c = (row >> 1) & 3;
  __shared__ float cw[KTOT];
  for (int j = threadIdx.x; j < KTOT; j += 256) cw[j] = conv2_w[(size_t)o*KTOT + j];
  __syncthreads();
  for (int k = threadIdx.x; k < KTOT; k += 256) {
    int kt = k >> 5, ks = (k >> 3) & 3, j = k & 7;
    int r = kt / 18, t2 = kt - r*18;
    int ibb = t2 / 3, s = t2 - ibb*3;
    int i = ibb*32 + ks*8 + j;
    int slot = row*4 + (ks ^ c);
    w2_re[(((size_t)kt*12 + chunk)*64 + slot)*8 + j] = (bf16)cw[i*9 + r*3 + s];
  }
}

// ---------------- pack+pad x: f32 NCHW -> bf16 [b][i/8][130][130][8], zero borders ----------------
__global__ void k_xpack(const float* __restrict__ x, bf16* __restrict__ xpack) {
  int h2 = blockIdx.x, ib = blockIdx.y, b = blockIdx.z;
  size_t rowbase = (((size_t)b*24 + ib)*HP + h2)*HP;
  int t = threadIdx.x;  // 128
  if (h2 == 0 || h2 == HP-1) {
    uint4 z = make_uint4(0,0,0,0);
    for (int w = t; w < HP; w += 128) *(uint4*)(xpack + (rowbase + w)*8) = z;
    return;
  }
  __shared__ float tt[8][128];
  int h = h2 - 1;
  #pragma unroll
  for (int ii = 0; ii < 8; ++ii)
    tt[ii][t] = x[(((size_t)b*CI + ib*8 + ii)*H_ + h)*W_ + t];
  __syncthreads();
  bf16x8 v;
  #pragma unroll
  for (int ii = 0; ii < 8; ++ii) v[ii] = (bf16)tt[ii][t];
  *(bf16x8*)(xpack + (rowbase + t + 1)*8) = v;
  if (t == 0) {
    uint4 z = make_uint4(0,0,0,0);
    *(uint4*)(xpack + rowbase*8) = z;
    *(uint4*)(xpack + (rowbase + HP-1)*8) = z;
  }
}

// ---------------- zero borders of midpack ----------------
__global__ void k_midborder(bf16* __restrict__ midpack) {
  int bi = blockIdx.x;  // b*24+ib
  size_t base = (size_t)bi * HPHP;
  uint4 z = make_uint4(0,0,0,0);
  for (int j = threadIdx.x; j < 516; j += 256) {
    int h2, w2;
    if (j < 130)      { h2 = 0;       w2 = j; }
    else if (j < 260) { h2 = 129;     w2 = j - 130; }
    else if (j < 388) { h2 = j - 259; w2 = 0; }
    else              { h2 = j - 387; w2 = 129; }
    *(uint4*)(midpack + (base + (size_t)h2*HP + w2)*8) = z;
  }
}

// ---------------- implicit-GEMM 3x3 conv, BM=192 x BN=256(2 rows), K order (r,ib,s) ----------------
// R12 structure (race-fixed prologue [B0,A0,A1], counted-vmcnt, 2-phase micro, T5 setprio)
// with 32x32x16 MFMA (R11's audited fragment mapping — its NaN was the prologue race,
// not the layout). 4 waves (2m x 2n), per-wave 96x128 = 3 mt x 4 nt tiles of 32x32.
// A frag (mt,kh): chunk = wm*6+mt*2+((l>>4)&1), row16 = l&15, kslot = kh*2+(l>>5),
//   baked slot-XOR -> row = lane&31, k = kslot*8+j. B frag (nt,kh): kg = kh*2+(l>>5),
//   col = nt*32+(l&31) (+s col shift). C/D: col = l&31, row = (reg&3)+8*(reg>>2)+4*(l>>5).
// Per micro: entry vmcnt(3)/(3)/(8|0) + BAR;
//   P1: kh=0 reads (3 af + 4 bv) ; stageA(u+2) ; BAR ; prio1 12 MFMA prio0
//   P2: kh=1 reads (3 af + 4 bv) ; stageB(m+1)@s1 ; BAR ; prio1 12 MFMA prio0
template<int MODE>
__global__ __launch_bounds__(256, 2)
void k_conv(const bf16* __restrict__ wre, const bf16* __restrict__ inpack,
            const float* __restrict__ bias_g, const bf16* __restrict__ respack,
            bf16* __restrict__ outpack, float* __restrict__ outp) {
  const int tid  = threadIdx.x;
  const int lane = tid & 63;
  const int wv   = tid >> 6;          // 0..3
  const int wm   = wv >> 1;           // 0..1 (o half)
  const int wn   = wv & 1;            // 0..1 (p half = image row)
  const int l15  = lane & 15;
  const int l31  = lane & 31;
  const int lhi  = lane >> 5;         // 0..1

  // XCD-aware chunked remap: 1024 blocks, 128/XCD => each XCD owns 2 batches
  const int bid  = blockIdx.x;
  const int n    = (bid & 7) * 128 + (bid >> 3);
  const int b    = n >> 6;
  const int tile = n & 63;
  const int p0   = tile * 256;
  const int h0   = tile * 2;

  __shared__ __align__(16) bf16 Alds[3][12*512];    // 36864 B
  __shared__ __align__(16) bf16 Blds[2][4*2560];    // 40960 B
  __shared__ float bias_lds[CO];

  if (tid < CO) bias_lds[tid] = (MODE == 0) ? bias_g[b*CO + tid] : bias_g[tid];

  const size_t wbase = (MODE == 0) ? ((size_t)b*CO*KTOT) : 0;

  // A staging: 12 chunks of 1KB per micro-step; wave wv stages {wv, wv+4, wv+8}
  const bf16* aS = wre + wbase + (size_t)wv*512 + lane*8;
  // B staging: wave wv stages kg=wv; 5 overlapped chunks over contiguous row-pair (4160B)
  const bf16* bbase = inpack + (((size_t)b*24 + wv)*HPHP + (size_t)h0*HP)*8 + lane*8;
  int ibm = 0; ptrdiff_t boffEl = 0;   // macro (r,ib) element offset

  auto stageA = [&](bf16* dbuf) {
    bf16* d = dbuf + wv*512;
    gll16(aS,        d);
    gll16(aS + 2048, d + 2048);
    gll16(aS + 4096, d + 4096);
    aS += 6144;
  };
  auto stageB = [&](bf16* dbuf) {
    const bf16* src = bbase + boffEl;
    bf16* d = dbuf + wv*2560;
    gll16(src,        d);
    gll16(src +  512, d +  512);
    gll16(src + 1024, d + 1024);
    gll16(src + 1536, d + 1536);
    gll16(src + 1568, d + 1568);   // overlapped tail chunk (3136..4159 B)
    if (++ibm == 6) { ibm = 0; boffEl += (ptrdiff_t)(HP - 20*HPHP)*8; }
    else boffEl += (ptrdiff_t)4*HPHP*8;
  };

  f32x16 acc[3][4];
  #pragma unroll
  for (int mt = 0; mt < 3; ++mt)
    #pragma unroll
    for (int nt = 0; nt < 4; ++nt)
      #pragma unroll
      for (int jj = 0; jj < 16; ++jj) acc[mt][nt][jj] = 0.f;

  // A-read constants: element offset within chunk for (row16, kslot) with baked slot-XOR
  const int arow   = l15;
  const int aswz   = (arow >> 1) & 3;
  const int achnk  = (lane >> 4) & 1;                 // +0/+1 chunk for rows 16-31
  const int aoff0  = arow*32 + ((lhi       ^ aswz) * 8);   // kh=0: kslot = 0..1
  const int aoff1  = arow*32 + (((2 + lhi) ^ aswz) * 8);   // kh=1: kslot = 2..3
  // B-read constants
  const int bcol   = (wn*130 + l31) * 8;              // (row=wn, col=l31) base, elements
  const int bkg    = lhi * 2560;                      // kg low bit from lane>>5

  // prologue FIFO: [B(0):5][A(0):3][A(1):3] — first entry vmcnt(3) drains B0+A0, keeps A1
  stageB(Blds[0]);
  stageA(Alds[0]);
  stageA(Alds[1]);

  bf16* Bcur = (bf16*)Blds[0];
  bf16* Bnxt = (bf16*)Blds[1];

  for (int m = 0; m < 18; ++m) {
    #pragma unroll
    for (int s = 0; s < 3; ++s) {
      // ---- entry wait + barrier (counted schedule, same as R12) ----
      if (s == 2) {
        if (m == 17) asm volatile("s_waitcnt vmcnt(0)" ::: "memory");
        else         asm volatile("s_waitcnt vmcnt(8)" ::: "memory");
      } else {
        asm volatile("s_waitcnt vmcnt(3)" ::: "memory");
      }
      __builtin_amdgcn_s_barrier();

      const bf16* A  = Alds[s];                        // u%3 == s
      const bf16* bp = Bcur + bkg + bcol + s*8;        // kh=1 adds +2*2560

      // ---- P1: kh=0 reads ; stageA(u+2) ; 12 MFMA ----
      bf16x8 a0 = *(const bf16x8*)(A + (wm*6 + 0 + achnk)*512 + aoff0);
      bf16x8 a1 = *(const bf16x8*)(A + (wm*6 + 2 + achnk)*512 + aoff0);
      bf16x8 a2 = *(const bf16x8*)(A + (wm*6 + 4 + achnk)*512 + aoff0);
      bf16x8 b0 = *(const bf16x8*)(bp);
      bf16x8 b1 = *(const bf16x8*)(bp + 256);
      bf16x8 b2 = *(const bf16x8*)(bp + 512);
      bf16x8 b3 = *(const bf16x8*)(bp + 768);

      if (3*m + s + 2 < NT) stageA(Alds[(s+2)%3]);     // A(u+2)

      __builtin_amdgcn_s_barrier();
      __builtin_amdgcn_s_setprio(1);
      acc[0][0] = __builtin_amdgcn_mfma_f32_32x32x16_bf16(a0, b0, acc[0][0], 0, 0, 0);
      acc[0][1] = __builtin_amdgcn_mfma_f32_32x32x16_bf16(a0, b1, acc[0][1], 0, 0, 0);
      acc[0][2] = __builtin_amdgcn_mfma_f32_32x32x16_bf16(a0, b2, acc[0][2], 0, 0, 0);
      acc[0][3] = __builtin_amdgcn_mfma_f32_32x32x16_bf16(a0, b3, acc[0][3], 0, 0, 0);
      acc[1][0] = __builtin_amdgcn_mfma_f32_32x32x16_bf16(a1, b0, acc[1][0], 0, 0, 0);
      acc[1][1] = __builtin_amdgcn_mfma_f32_32x32x16_bf16(a1, b1, acc[1][1], 0, 0, 0);
      acc[1][2] = __builtin_amdgcn_mfma_f32_32x32x16_bf16(a1, b2, acc[1][2], 0, 0, 0);
      acc[1][3] = __builtin_amdgcn_mfma_f32_32x32x16_bf16(a1, b3, acc[1][3], 0, 0, 0);
      acc[2][0] = __builtin_amdgcn_mfma_f32_32x32x16_bf16(a2, b0, acc[2][0], 0, 0, 0);
      acc[2][1] = __builtin_amdgcn_mfma_f32_32x32x16_bf16(a2, b1, acc[2][1], 0, 0, 0);
      acc[2][2] = __builtin_amdgcn_mfma_f32_32x32x16_bf16(a2, b2, acc[2][2], 0, 0, 0);
      acc[2][3] = __builtin_amdgcn_mfma_f32_32x32x16_bf16(a2, b3, acc[2][3], 0, 0, 0);
      __builtin_amdgcn_s_setprio(0);

      // ---- P2: kh=1 reads ; stageB(m+1)@s1 ; 12 MFMA ----
      bf16x8 a3 = *(const bf16x8*)(A + (wm*6 + 0 + achnk)*512 + aoff1);
      bf16x8 a4 = *(const bf16x8*)(A + (wm*6 + 2 + achnk)*512 + aoff1);
      bf16x8 a5 = *(const bf16x8*)(A + (wm*6 + 4 + achnk)*512 + aoff1);
      bf16x8 b4 = *(const bf16x8*)(bp + 2*2560);
      bf16x8 b5 = *(const bf16x8*)(bp + 2*2560 + 256);
      bf16x8 b6 = *(const bf16x8*)(bp + 2*2560 + 512);
      bf16x8 b7 = *(const bf16x8*)(bp + 2*2560 + 768);

      if (s == 1 && m < 17) stageB(Bnxt);              // B(m+1)

      __builtin_amdgcn_s_barrier();
      __builtin_amdgcn_s_setprio(1);
      acc[0][0] = __builtin_amdgcn_mfma_f32_32x32x16_bf16(a3, b4, acc[0][0], 0, 0, 0);
      acc[0][1] = __builtin_amdgcn_mfma_f32_32x32x16_bf16(a3, b5, acc[0][1], 0, 0, 0);
      acc[0][2] = __builtin_amdgcn_mfma_f32_32x32x16_bf16(a3, b6, acc[0][2], 0, 0, 0);
      acc[0][3] = __builtin_amdgcn_mfma_f32_32x32x16_bf16(a3, b7, acc[0][3], 0, 0, 0);
      acc[1][0] = __builtin_amdgcn_mfma_f32_32x32x16_bf16(a4, b4, acc[1][0], 0, 0, 0);
      acc[1][1] = __builtin_amdgcn_mfma_f32_32x32x16_bf16(a4, b5, acc[1][1], 0, 0, 0);
      acc[1][2] = __builtin_amdgcn_mfma_f32_32x32x16_bf16(a4, b6, acc[1][2], 0, 0, 0);
      acc[1][3] = __builtin_amdgcn_mfma_f32_32x32x16_bf16(a4, b7, acc[1][3], 0, 0, 0);
      acc[2][0] = __builtin_amdgcn_mfma_f32_32x32x16_bf16(a5, b4, acc[2][0], 0, 0, 0);
      acc[2][1] = __builtin_amdgcn_mfma_f32_32x32x16_bf16(a5, b5, acc[2][1], 0, 0, 0);
      acc[2][2] = __builtin_amdgcn_mfma_f32_32x32x16_bf16(a5, b6, acc[2][2], 0, 0, 0);
      acc[2][3] = __builtin_amdgcn_mfma_f32_32x32x16_bf16(a5, b7, acc[2][3], 0, 0, 0);
      __builtin_amdgcn_s_setprio(0);
    }
    { bf16* t = Bcur; Bcur = Bnxt; Bnxt = t; }
  }

  // epilogue: C/D 32x32 mapping: col=l31, row=(reg&3)+8*(reg>>2)+4*lhi
  #pragma unroll
  for (int mt = 0; mt < 3; ++mt) {
    #pragma unroll
    for (int nt = 0; nt < 4; ++nt) {
      int w = nt*32 + l31;
      int p = p0 + wn*128 + w;
      #pragma unroll
      for (int rq = 0; rq < 4; ++rq) {
        int ob = wm*96 + mt*32 + rq*8 + 4*lhi;     // 4 consecutive channels
        size_t basep = (((size_t)b*24 + (ob >> 3))*HP + (h0 + wn + 1))*HP + (w + 1);
        if (MODE == 0) {
          bf16x4 pk;
          #pragma unroll
          for (int jj = 0; jj < 4; ++jj) {
            float xv = acc[mt][nt][rq*4 + jj] + bias_lds[ob + jj];
            pk[jj] = (bf16)silu_f(xv);
          }
          *(bf16x4*)(outpack + basep*8 + (ob & 7)) = pk;
        } else {
          bf16x4 rr = *(const bf16x4*)(respack + basep*8 + (ob & 7));
          #pragma unroll
          for (int jj = 0; jj < 4; ++jj) {
            float xv = silu_f(acc[mt][nt][rq*4 + jj] + bias_lds[ob + jj]);
            size_t idx = ((size_t)b*CO + ob + jj)*NPX + p;
            outp[idx] = xv + (float)rr[jj];
          }
        }
      }
    }
  }
}

extern "C" void kernel_launch(void* const* d_in, const int* in_sizes, int n_in,
                              void* d_out, int out_size, void* d_ws, size_t ws_size,
                              hipStream_t stream) {
  const float* x        = (const float*)d_in[0];
  const float* latent   = (const float*)d_in[1];
  const float* expert_w = (const float*)d_in[2];
  const float* expert_b = (const float*)d_in[3];
  const float* attn_w   = (const float*)d_in[4];
  const float* attn_b   = (const float*)d_in[5];
  const float* conv2_w  = (const float*)d_in[6];
  const float* conv2_b  = (const float*)d_in[7];
  float* outp = (float*)d_out;

  char* base = (char*)d_ws;
  size_t off = 0;
  float* attn = (float*)(base + off); off += 4096;
  float* bdyn = (float*)(base + off); off += 16384;
  bf16* w_re  = (bf16*)(base + off);  off += (size_t)B_*CO*KTOT*2;      // 10.6 MB
  bf16* w2_re = (bf16*)(base + off);  off += (size_t)CO*KTOT*2;         // 0.66 MB
  bf16* xpack = (bf16*)(base + off);  off += (size_t)B_*24*HPHP*8*2;    // 103.8 MB
  bf16* midpack = (bf16*)(base + off); off += (size_t)B_*24*HPHP*8*2;   // 103.8 MB
  (void)ws_size; (void)in_sizes; (void)n_in; (void)out_size;

  k_attn<<<dim3(1), dim3(128), 0, stream>>>(latent, attn_w, attn_b, attn);
  k_bdyn<<<dim3(12), dim3(256), 0, stream>>>(attn, expert_b, bdyn);
  k_wdyn<<<dim3(CO), dim3(256), 0, stream>>>(expert_w, attn, w_re);
  k_w2re<<<dim3(CO), dim3(256), 0, stream>>>(conv2_w, w2_re);
  k_xpack<<<dim3(130, 24, 16), dim3(128), 0, stream>>>(x, xpack);
  k_midborder<<<dim3(B_*24), dim3(256), 0, stream>>>(midpack);
  k_conv<0><<<dim3(1024), dim3(256), 0, stream>>>(w_re, xpack, bdyn, xpack, midpack, outp);
  k_conv<1><<<dim3(1024), dim3(256), 0, stream>>>(w2_re, midpack, conv2_b, xpack, midpack, outp);
}

// Round 14
// 459.728 us; speedup vs baseline: 1.1820x; 1.0508x over previous
//
#include <hip/hip_runtime.h>
#include <stdint.h>
#include <stddef.h>

typedef __bf16 bf16;
typedef bf16 bf16x8 __attribute__((ext_vector_type(8)));
typedef bf16 bf16x4 __attribute__((ext_vector_type(4)));
typedef float f32x4 __attribute__((ext_vector_type(4)));
typedef float f32x16 __attribute__((ext_vector_type(16)));

#define B_   16
#define CI   192
#define CO   192
#define H_   128
#define W_   128
#define KE   8
#define LD   64
#define KTOT 1728   // 9*192
#define HP   130    // padded H/W
#define HPHP (HP*HP)
#define NPX  (H_*W_)
#define NT   54     // K micro-steps of 32 (order: r-major, ib, s-minor)

__device__ __forceinline__ void gll16(const void* g, void* l) {
  __builtin_amdgcn_global_load_lds(
      (const __attribute__((address_space(1))) unsigned int*)g,
      (__attribute__((address_space(3))) unsigned int*)l, 16, 0, 0);
}

__device__ __forceinline__ float silu_f(float x) {
  return x / (1.f + __expf(-x));
}

// compute attn[b][k] (softmax over k of latent@attn_w^T + attn_b) into LDS, threads 0..127
__device__ __forceinline__ void attn_inline(const float* __restrict__ latent,
                                            const float* __restrict__ attn_w,
                                            const float* __restrict__ attn_b,
                                            float (*al)[KE], int tid) {
  if (tid < 128) {
    int b = tid >> 3, k = tid & 7;
    float s = attn_b[k];
    #pragma unroll 8
    for (int d = 0; d < LD; ++d) s += latent[b*LD + d] * attn_w[k*LD + d];
    float m = s;
    for (int off = 4; off; off >>= 1) m = fmaxf(m, __shfl_xor(m, off, 8));
    float e = __expf(s - m);
    float sum = e;
    for (int off = 4; off; off >>= 1) sum += __shfl_xor(sum, off, 8);
    al[b][k] = e / sum;
  }
  __syncthreads();
}

// ---------------- dynamic bias (attn inlined) ----------------
__global__ void k_bdyn(const float* __restrict__ latent, const float* __restrict__ attn_w,
                       const float* __restrict__ attn_b, const float* __restrict__ expert_b,
                       float* __restrict__ bdyn) {
  __shared__ float al[B_][KE];
  attn_inline(latent, attn_w, attn_b, al, threadIdx.x);
  int j = blockIdx.x * 256 + threadIdx.x;
  if (j >= B_ * CO) return;
  int b = j / CO, o = j - b * CO;
  float s = 0.f;
  #pragma unroll
  for (int e = 0; e < KE; ++e) s += al[b][e] * expert_b[e*CO + o];
  bdyn[j] = s;
}

// ---------------- dynamic weights -> staged layout [b][kt=54][chunk=12][slot=64][8] bf16
// K order: kt = r*18 + ib*3 + s  (s innermost). slot L holds (row=L>>2, ks=(L&3)^((row>>1)&3)).
// element: o = chunk*16+row, i = ib*32 + ks*8 + j, weight (o, i, r, s). attn inlined.
__global__ void k_wdyn(const float* __restrict__ expert_w, const float* __restrict__ latent,
                       const float* __restrict__ attn_w, const float* __restrict__ attn_b,
                       bf16* __restrict__ w_re) {
  int o = blockIdx.x;            // 192
  int chunk = o >> 4, row = o & 15, c = (row >> 1) & 3;
  __shared__ float ew[KE][KTOT];
  __shared__ float al[B_][KE];
  attn_inline(latent, attn_w, attn_b, al, threadIdx.x);
  for (int e = 0; e < KE; ++e)
    for (int j = threadIdx.x; j < KTOT; j += 256)
      ew[e][j] = expert_w[((size_t)e*CO + o)*KTOT + j];   // [i*9+rs]
  __syncthreads();
  for (int idx = threadIdx.x; idx < B_*KTOT; idx += 256) {
    int b = idx / KTOT, k = idx - b*KTOT;
    int kt = k >> 5, ks = (k >> 3) & 3, j = k & 7;
    int r = kt / 18, t2 = kt - r*18;
    int ibb = t2 / 3, s = t2 - ibb*3;
    int i = ibb*32 + ks*8 + j;
    float acc = 0.f;
    #pragma unroll
    for (int e = 0; e < KE; ++e) acc += al[b][e] * ew[e][i*9 + r*3 + s];
    int slot = row*4 + (ks ^ c);
    w_re[((((size_t)b*NT + kt)*12 + chunk)*64 + slot)*8 + j] = (bf16)acc;
  }
}

// ---------------- static conv2 weights -> same staged layout (no b) ----------------
__global__ void k_w2re(const float* __restrict__ conv2_w, bf16* __restrict__ w2_re) {
  int o = blockIdx.x;
  int chunk = o >> 4, row = o & 15, c = (row >> 1) & 3;
  __shared__ float cw[KTOT];
  for (int j = threadIdx.x; j < KTOT; j += 256) cw[j] = conv2_w[(size_t)o*KTOT + j];
  __syncthreads();
  for (int k = threadIdx.x; k < KTOT; k += 256) {
    int kt = k >> 5, ks = (k >> 3) & 3, j = k & 7;
    int r = kt / 18, t2 = kt - r*18;
    int ibb = t2 / 3, s = t2 - ibb*3;
    int i = ibb*32 + ks*8 + j;
    int slot = row*4 + (ks ^ c);
    w2_re[(((size_t)kt*12 + chunk)*64 + slot)*8 + j] = (bf16)cw[i*9 + r*3 + s];
  }
}

// ---------------- pack+pad x -> xpack bf16 [b][i/8][130][130][8]; also zero midpack borders ----
__global__ void k_xpack(const float* __restrict__ x, bf16* __restrict__ xpack,
                        bf16* __restrict__ midpack) {
  int h2 = blockIdx.x, ib = blockIdx.y, b = blockIdx.z;
  size_t rowbase = (((size_t)b*24 + ib)*HP + h2)*HP;
  int t = threadIdx.x;  // 128
  uint4 z = make_uint4(0,0,0,0);
  if (h2 == 0 || h2 == HP-1) {
    for (int w = t; w < HP; w += 128) {
      *(uint4*)(xpack   + (rowbase + w)*8) = z;
      *(uint4*)(midpack + (rowbase + w)*8) = z;
    }
    return;
  }
  __shared__ float tt[8][128];
  int h = h2 - 1;
  #pragma unroll
  for (int ii = 0; ii < 8; ++ii)
    tt[ii][t] = x[(((size_t)b*CI + ib*8 + ii)*H_ + h)*W_ + t];
  __syncthreads();
  bf16x8 v;
  #pragma unroll
  for (int ii = 0; ii < 8; ++ii) v[ii] = (bf16)tt[ii][t];
  *(bf16x8*)(xpack + (rowbase + t + 1)*8) = v;
  if (t == 0) {
    *(uint4*)(xpack + rowbase*8) = z;
    *(uint4*)(xpack + (rowbase + HP-1)*8) = z;
    *(uint4*)(midpack + rowbase*8) = z;
    *(uint4*)(midpack + (rowbase + HP-1)*8) = z;
  }
}

// ---------------- implicit-GEMM 3x3 conv, BM=192 x BN=256(2 rows), K order (r,ib,s) ----------------
// R13 kernel, byte-identical (verified 209us/conv, absmax 0.031):
// race-fixed prologue [B0,A0,A1], counted-vmcnt, 2-phase micro, T5 setprio, 32x32x16 MFMA.
// 4 waves (2m x 2n), per-wave 96x128 = 3 mt x 4 nt tiles of 32x32.
// A frag (mt,kh): chunk = wm*6+mt*2+((l>>4)&1), row16 = l&15, kslot = kh*2+(l>>5),
//   baked slot-XOR -> row = lane&31, k = kslot*8+j. B frag (nt,kh): kg = kh*2+(l>>5),
//   col = nt*32+(l&31) (+s col shift). C/D: col = l&31, row = (reg&3)+8*(reg>>2)+4*(l>>5).
// Per micro: entry vmcnt(3)/(3)/(8|0) + BAR;
//   P1: kh=0 reads (3 af + 4 bv) ; stageA(u+2) ; BAR ; prio1 12 MFMA prio0
//   P2: kh=1 reads (3 af + 4 bv) ; stageB(m+1)@s1 ; BAR ; prio1 12 MFMA prio0
template<int MODE>
__global__ __launch_bounds__(256, 2)
void k_conv(const bf16* __restrict__ wre, const bf16* __restrict__ inpack,
            const float* __restrict__ bias_g, const bf16* __restrict__ respack,
            bf16* __restrict__ outpack, float* __restrict__ outp) {
  const int tid  = threadIdx.x;
  const int lane = tid & 63;
  const int wv   = tid >> 6;          // 0..3
  const int wm   = wv >> 1;           // 0..1 (o half)
  const int wn   = wv & 1;            // 0..1 (p half = image row)
  const int l15  = lane & 15;
  const int l31  = lane & 31;
  const int lhi  = lane >> 5;         // 0..1

  // XCD-aware chunked remap: 1024 blocks, 128/XCD => each XCD owns 2 batches
  const int bid  = blockIdx.x;
  const int n    = (bid & 7) * 128 + (bid >> 3);
  const int b    = n >> 6;
  const int tile = n & 63;
  const int p0   = tile * 256;
  const int h0   = tile * 2;

  __shared__ __align__(16) bf16 Alds[3][12*512];    // 36864 B
  __shared__ __align__(16) bf16 Blds[2][4*2560];    // 40960 B
  __shared__ float bias_lds[CO];

  if (tid < CO) bias_lds[tid] = (MODE == 0) ? bias_g[b*CO + tid] : bias_g[tid];

  const size_t wbase = (MODE == 0) ? ((size_t)b*CO*KTOT) : 0;

  // A staging: 12 chunks of 1KB per micro-step; wave wv stages {wv, wv+4, wv+8}
  const bf16* aS = wre + wbase + (size_t)wv*512 + lane*8;
  // B staging: wave wv stages kg=wv; 5 overlapped chunks over contiguous row-pair (4160B)
  const bf16* bbase = inpack + (((size_t)b*24 + wv)*HPHP + (size_t)h0*HP)*8 + lane*8;
  int ibm = 0; ptrdiff_t boffEl = 0;   // macro (r,ib) element offset

  auto stageA = [&](bf16* dbuf) {
    bf16* d = dbuf + wv*512;
    gll16(aS,        d);
    gll16(aS + 2048, d + 2048);
    gll16(aS + 4096, d + 4096);
    aS += 6144;
  };
  auto stageB = [&](bf16* dbuf) {
    const bf16* src = bbase + boffEl;
    bf16* d = dbuf + wv*2560;
    gll16(src,        d);
    gll16(src +  512, d +  512);
    gll16(src + 1024, d + 1024);
    gll16(src + 1536, d + 1536);
    gll16(src + 1568, d + 1568);   // overlapped tail chunk (3136..4159 B)
    if (++ibm == 6) { ibm = 0; boffEl += (ptrdiff_t)(HP - 20*HPHP)*8; }
    else boffEl += (ptrdiff_t)4*HPHP*8;
  };

  f32x16 acc[3][4];
  #pragma unroll
  for (int mt = 0; mt < 3; ++mt)
    #pragma unroll
    for (int nt = 0; nt < 4; ++nt)
      #pragma unroll
      for (int jj = 0; jj < 16; ++jj) acc[mt][nt][jj] = 0.f;

  // A-read constants: element offset within chunk for (row16, kslot) with baked slot-XOR
  const int arow   = l15;
  const int aswz   = (arow >> 1) & 3;
  const int achnk  = (lane >> 4) & 1;                 // +0/+1 chunk for rows 16-31
  const int aoff0  = arow*32 + ((lhi       ^ aswz) * 8);   // kh=0: kslot = 0..1
  const int aoff1  = arow*32 + (((2 + lhi) ^ aswz) * 8);   // kh=1: kslot = 2..3
  // B-read constants
  const int bcol   = (wn*130 + l31) * 8;              // (row=wn, col=l31) base, elements
  const int bkg    = lhi * 2560;                      // kg low bit from lane>>5

  // prologue FIFO: [B(0):5][A(0):3][A(1):3] — first entry vmcnt(3) drains B0+A0, keeps A1
  stageB(Blds[0]);
  stageA(Alds[0]);
  stageA(Alds[1]);

  bf16* Bcur = (bf16*)Blds[0];
  bf16* Bnxt = (bf16*)Blds[1];

  for (int m = 0; m < 18; ++m) {
    #pragma unroll
    for (int s = 0; s < 3; ++s) {
      // ---- entry wait + barrier (counted schedule) ----
      if (s == 2) {
        if (m == 17) asm volatile("s_waitcnt vmcnt(0)" ::: "memory");
        else         asm volatile("s_waitcnt vmcnt(8)" ::: "memory");
      } else {
        asm volatile("s_waitcnt vmcnt(3)" ::: "memory");
      }
      __builtin_amdgcn_s_barrier();

      const bf16* A  = Alds[s];                        // u%3 == s
      const bf16* bp = Bcur + bkg + bcol + s*8;        // kh=1 adds +2*2560

      // ---- P1: kh=0 reads ; stageA(u+2) ; 12 MFMA ----
      bf16x8 a0 = *(const bf16x8*)(A + (wm*6 + 0 + achnk)*512 + aoff0);
      bf16x8 a1 = *(const bf16x8*)(A + (wm*6 + 2 + achnk)*512 + aoff0);
      bf16x8 a2 = *(const bf16x8*)(A + (wm*6 + 4 + achnk)*512 + aoff0);
      bf16x8 b0 = *(const bf16x8*)(bp);
      bf16x8 b1 = *(const bf16x8*)(bp + 256);
      bf16x8 b2 = *(const bf16x8*)(bp + 512);
      bf16x8 b3 = *(const bf16x8*)(bp + 768);

      if (3*m + s + 2 < NT) stageA(Alds[(s+2)%3]);     // A(u+2)

      __builtin_amdgcn_s_barrier();
      __builtin_amdgcn_s_setprio(1);
      acc[0][0] = __builtin_amdgcn_mfma_f32_32x32x16_bf16(a0, b0, acc[0][0], 0, 0, 0);
      acc[0][1] = __builtin_amdgcn_mfma_f32_32x32x16_bf16(a0, b1, acc[0][1], 0, 0, 0);
      acc[0][2] = __builtin_amdgcn_mfma_f32_32x32x16_bf16(a0, b2, acc[0][2], 0, 0, 0);
      acc[0][3] = __builtin_amdgcn_mfma_f32_32x32x16_bf16(a0, b3, acc[0][3], 0, 0, 0);
      acc[1][0] = __builtin_amdgcn_mfma_f32_32x32x16_bf16(a1, b0, acc[1][0], 0, 0, 0);
      acc[1][1] = __builtin_amdgcn_mfma_f32_32x32x16_bf16(a1, b1, acc[1][1], 0, 0, 0);
      acc[1][2] = __builtin_amdgcn_mfma_f32_32x32x16_bf16(a1, b2, acc[1][2], 0, 0, 0);
      acc[1][3] = __builtin_amdgcn_mfma_f32_32x32x16_bf16(a1, b3, acc[1][3], 0, 0, 0);
      acc[2][0] = __builtin_amdgcn_mfma_f32_32x32x16_bf16(a2, b0, acc[2][0], 0, 0, 0);
      acc[2][1] = __builtin_amdgcn_mfma_f32_32x32x16_bf16(a2, b1, acc[2][1], 0, 0, 0);
      acc[2][2] = __builtin_amdgcn_mfma_f32_32x32x16_bf16(a2, b2, acc[2][2], 0, 0, 0);
      acc[2][3] = __builtin_amdgcn_mfma_f32_32x32x16_bf16(a2, b3, acc[2][3], 0, 0, 0);
      __builtin_amdgcn_s_setprio(0);

      // ---- P2: kh=1 reads ; stageB(m+1)@s1 ; 12 MFMA ----
      bf16x8 a3 = *(const bf16x8*)(A + (wm*6 + 0 + achnk)*512 + aoff1);
      bf16x8 a4 = *(const bf16x8*)(A + (wm*6 + 2 + achnk)*512 + aoff1);
      bf16x8 a5 = *(const bf16x8*)(A + (wm*6 + 4 + achnk)*512 + aoff1);
      bf16x8 b4 = *(const bf16x8*)(bp + 2*2560);
      bf16x8 b5 = *(const bf16x8*)(bp + 2*2560 + 256);
      bf16x8 b6 = *(const bf16x8*)(bp + 2*2560 + 512);
      bf16x8 b7 = *(const bf16x8*)(bp + 2*2560 + 768);

      if (s == 1 && m < 17) stageB(Bnxt);              // B(m+1)

      __builtin_amdgcn_s_barrier();
      __builtin_amdgcn_s_setprio(1);
      acc[0][0] = __builtin_amdgcn_mfma_f32_32x32x16_bf16(a3, b4, acc[0][0], 0, 0, 0);
      acc[0][1] = __builtin_amdgcn_mfma_f32_32x32x16_bf16(a3, b5, acc[0][1], 0, 0, 0);
      acc[0][2] = __builtin_amdgcn_mfma_f32_32x32x16_bf16(a3, b6, acc[0][2], 0, 0, 0);
      acc[0][3] = __builtin_amdgcn_mfma_f32_32x32x16_bf16(a3, b7, acc[0][3], 0, 0, 0);
      acc[1][0] = __builtin_amdgcn_mfma_f32_32x32x16_bf16(a4, b4, acc[1][0], 0, 0, 0);
      acc[1][1] = __builtin_amdgcn_mfma_f32_32x32x16_bf16(a4, b5, acc[1][1], 0, 0, 0);
      acc[1][2] = __builtin_amdgcn_mfma_f32_32x32x16_bf16(a4, b6, acc[1][2], 0, 0, 0);
      acc[1][3] = __builtin_amdgcn_mfma_f32_32x32x16_bf16(a4, b7, acc[1][3], 0, 0, 0);
      acc[2][0] = __builtin_amdgcn_mfma_f32_32x32x16_bf16(a5, b4, acc[2][0], 0, 0, 0);
      acc[2][1] = __builtin_amdgcn_mfma_f32_32x32x16_bf16(a5, b5, acc[2][1], 0, 0, 0);
      acc[2][2] = __builtin_amdgcn_mfma_f32_32x32x16_bf16(a5, b6, acc[2][2], 0, 0, 0);
      acc[2][3] = __builtin_amdgcn_mfma_f32_32x32x16_bf16(a5, b7, acc[2][3], 0, 0, 0);
      __builtin_amdgcn_s_setprio(0);
    }
    { bf16* t = Bcur; Bcur = Bnxt; Bnxt = t; }
  }

  // epilogue: C/D 32x32 mapping: col=l31, row=(reg&3)+8*(reg>>2)+4*lhi
  #pragma unroll
  for (int mt = 0; mt < 3; ++mt) {
    #pragma unroll
    for (int nt = 0; nt < 4; ++nt) {
      int w = nt*32 + l31;
      int p = p0 + wn*128 + w;
      #pragma unroll
      for (int rq = 0; rq < 4; ++rq) {
        int ob = wm*96 + mt*32 + rq*8 + 4*lhi;     // 4 consecutive channels
        size_t basep = (((size_t)b*24 + (ob >> 3))*HP + (h0 + wn + 1))*HP + (w + 1);
        if (MODE == 0) {
          bf16x4 pk;
          #pragma unroll
          for (int jj = 0; jj < 4; ++jj) {
            float xv = acc[mt][nt][rq*4 + jj] + bias_lds[ob + jj];
            pk[jj] = (bf16)silu_f(xv);
          }
          *(bf16x4*)(outpack + basep*8 + (ob & 7)) = pk;
        } else {
          bf16x4 rr = *(const bf16x4*)(respack + basep*8 + (ob & 7));
          #pragma unroll
          for (int jj = 0; jj < 4; ++jj) {
            float xv = silu_f(acc[mt][nt][rq*4 + jj] + bias_lds[ob + jj]);
            size_t idx = ((size_t)b*CO + ob + jj)*NPX + p;
            outp[idx] = xv + (float)rr[jj];
          }
        }
      }
    }
  }
}

extern "C" void kernel_launch(void* const* d_in, const int* in_sizes, int n_in,
                              void* d_out, int out_size, void* d_ws, size_t ws_size,
                              hipStream_t stream) {
  const float* x        = (const float*)d_in[0];
  const float* latent   = (const float*)d_in[1];
  const float* expert_w = (const float*)d_in[2];
  const float* expert_b = (const float*)d_in[3];
  const float* attn_w   = (const float*)d_in[4];
  const float* attn_b   = (const float*)d_in[5];
  const float* conv2_w  = (const float*)d_in[6];
  const float* conv2_b  = (const float*)d_in[7];
  float* outp = (float*)d_out;

  char* base = (char*)d_ws;
  size_t off = 0;
  float* bdyn = (float*)(base + off); off += 16384;
  bf16* w_re  = (bf16*)(base + off);  off += (size_t)B_*CO*KTOT*2;      // 10.6 MB
  bf16* w2_re = (bf16*)(base + off);  off += (size_t)CO*KTOT*2;         // 0.66 MB
  bf16* xpack = (bf16*)(base + off);  off += (size_t)B_*24*HPHP*8*2;    // 103.8 MB
  bf16* midpack = (bf16*)(base + off); off += (size_t)B_*24*HPHP*8*2;   // 103.8 MB
  (void)ws_size; (void)in_sizes; (void)n_in; (void)out_size;

  k_xpack<<<dim3(130, 24, 16), dim3(128), 0, stream>>>(x, xpack, midpack);
  k_wdyn<<<dim3(CO), dim3(256), 0, stream>>>(expert_w, latent, attn_w, attn_b, w_re);
  k_bdyn<<<dim3(12), dim3(256), 0, stream>>>(latent, attn_w, attn_b, expert_b, bdyn);
  k_w2re<<<dim3(CO), dim3(256), 0, stream>>>(conv2_w, w2_re);
  k_conv<0><<<dim3(1024), dim3(256), 0, stream>>>(w_re, xpack, bdyn, xpack, midpack, outp);
  k_conv<1><<<dim3(1024), dim3(256), 0, stream>>>(w2_re, midpack, conv2_b, xpack, midpack, outp);
}